// Round 1
// baseline (391.474 us; speedup 1.0000x reference)
//
#include <hip/hip_runtime.h>
#include <hip/hip_bf16.h>

#define B_    4
#define S_    2048
#define HID_  512
#define NH_   8
#define HD_   64
#define MAXREL 512
#define TBL   1025
#define M_    (B_ * S_)   // 8192 tokens

typedef __attribute__((ext_vector_type(8))) short bf8;            // 8 bf16 (MFMA A/B frag)
typedef __attribute__((ext_vector_type(4))) float f4;             // MFMA C/D frag
typedef __attribute__((ext_vector_type(8))) unsigned short u16x8; // 16B copy unit

static __device__ __forceinline__ unsigned short f2bf(float f) {
    union { float f; unsigned int u; } v; v.f = f;
    unsigned int u = v.u;
    unsigned int r = (u + 0x7FFFu + ((u >> 16) & 1u)) >> 16;   // round-nearest-even
    return (unsigned short)r;
}

// ---------------- cast hidden_states fp32 -> bf16 ----------------
__global__ void k_cast_hs(const float* __restrict__ src, unsigned short* __restrict__ dst, int n4) {
    int i = blockIdx.x * blockDim.x + threadIdx.x;
    if (i >= n4) return;
    float4 v = ((const float4*)src)[i];
    ushort4 o;
    o.x = f2bf(v.x); o.y = f2bf(v.y); o.z = f2bf(v.z); o.w = f2bf(v.w);
    ((ushort4*)dst)[i] = o;
}

// ---------------- transpose + cast weight: Wt[n][k] = bf16(W[k][n]) ----------------
__global__ void k_transpose_w(const float* __restrict__ W, unsigned short* __restrict__ Wt) {
    int t = blockIdx.x * blockDim.x + threadIdx.x;   // 512*512
    int n = t >> 9, k = t & 511;
    Wt[t] = f2bf(W[k * HID_ + n]);
    (void)n;
}

// ---------------- QKV projection GEMM (bf16 MFMA, fp32 accum) ----------------
// A: hs bf16 [8192,512]; Wt: [512(n),512(k)]; out layouts:
//   z=0: Q[b,h,s,d]  z=1: K[b,h,s,d]  z=2: Vt[b,h,d,s]
__global__ __launch_bounds__(256) void k_gemm_qkv(
    const unsigned short* __restrict__ Abf,
    const unsigned short* __restrict__ Wqt, const unsigned short* __restrict__ Wkt,
    const unsigned short* __restrict__ Wvt,
    const float* __restrict__ bq, const float* __restrict__ bk, const float* __restrict__ bv,
    unsigned short* __restrict__ Q, unsigned short* __restrict__ K, unsigned short* __restrict__ Vt)
{
    const int z = blockIdx.z;
    const unsigned short* Wt = (z == 0) ? Wqt : ((z == 1) ? Wkt : Wvt);
    const float* bias = (z == 0) ? bq : ((z == 1) ? bk : bv);
    const int lane = threadIdx.x & 63, w = threadIdx.x >> 6;
    const int wr = w >> 1, wc = w & 1;
    const int m0 = blockIdx.x * 64 + wr * 32;
    const int n0 = blockIdx.y * 64 + wc * 32;
    const int lr = lane & 15, lg = lane >> 4;

    f4 acc[2][2] = {};
    for (int k0 = 0; k0 < HID_; k0 += 32) {
        const int kk = k0 + lg * 8;
        bf8 a0 = *(const bf8*)&Abf[(size_t)(m0 + lr) * HID_ + kk];
        bf8 a1 = *(const bf8*)&Abf[(size_t)(m0 + 16 + lr) * HID_ + kk];
        bf8 b0 = *(const bf8*)&Wt[(size_t)(n0 + lr) * HID_ + kk];
        bf8 b1 = *(const bf8*)&Wt[(size_t)(n0 + 16 + lr) * HID_ + kk];
        acc[0][0] = __builtin_amdgcn_mfma_f32_16x16x32_bf16(a0, b0, acc[0][0], 0, 0, 0);
        acc[0][1] = __builtin_amdgcn_mfma_f32_16x16x32_bf16(a0, b1, acc[0][1], 0, 0, 0);
        acc[1][0] = __builtin_amdgcn_mfma_f32_16x16x32_bf16(a1, b0, acc[1][0], 0, 0, 0);
        acc[1][1] = __builtin_amdgcn_mfma_f32_16x16x32_bf16(a1, b1, acc[1][1], 0, 0, 0);
    }
    for (int mi = 0; mi < 2; ++mi)
    for (int ni = 0; ni < 2; ++ni)
    for (int r = 0; r < 4; ++r) {
        int row = m0 + mi * 16 + lg * 4 + r;     // token
        int col = n0 + ni * 16 + lr;             // hid
        float v = acc[mi][ni][r] + bias[col];
        unsigned short bf = f2bf(v);
        int b = row >> 11, s = row & 2047;
        int h = col >> 6, d = col & 63;
        if (z == 2) {
            Vt[(((size_t)(b * NH_ + h)) * HD_ + d) * S_ + s] = bf;
        } else {
            unsigned short* dst = (z == 0) ? Q : K;
            dst[(((size_t)(b * NH_ + h)) * S_ + s) * HD_ + d] = bf;
        }
    }
}

// ---------------- output projection GEMM: out fp32 [8192,512] ----------------
__global__ __launch_bounds__(256) void k_gemm_out(
    const unsigned short* __restrict__ Abf,   // ctx bf16 [8192,512]
    const unsigned short* __restrict__ Wot,
    const float* __restrict__ bo,
    float* __restrict__ out)
{
    const int lane = threadIdx.x & 63, w = threadIdx.x >> 6;
    const int wr = w >> 1, wc = w & 1;
    const int m0 = blockIdx.x * 64 + wr * 32;
    const int n0 = blockIdx.y * 64 + wc * 32;
    const int lr = lane & 15, lg = lane >> 4;

    f4 acc[2][2] = {};
    for (int k0 = 0; k0 < HID_; k0 += 32) {
        const int kk = k0 + lg * 8;
        bf8 a0 = *(const bf8*)&Abf[(size_t)(m0 + lr) * HID_ + kk];
        bf8 a1 = *(const bf8*)&Abf[(size_t)(m0 + 16 + lr) * HID_ + kk];
        bf8 b0 = *(const bf8*)&Wot[(size_t)(n0 + lr) * HID_ + kk];
        bf8 b1 = *(const bf8*)&Wot[(size_t)(n0 + 16 + lr) * HID_ + kk];
        acc[0][0] = __builtin_amdgcn_mfma_f32_16x16x32_bf16(a0, b0, acc[0][0], 0, 0, 0);
        acc[0][1] = __builtin_amdgcn_mfma_f32_16x16x32_bf16(a0, b1, acc[0][1], 0, 0, 0);
        acc[1][0] = __builtin_amdgcn_mfma_f32_16x16x32_bf16(a1, b0, acc[1][0], 0, 0, 0);
        acc[1][1] = __builtin_amdgcn_mfma_f32_16x16x32_bf16(a1, b1, acc[1][1], 0, 0, 0);
    }
    for (int mi = 0; mi < 2; ++mi)
    for (int ni = 0; ni < 2; ++ni)
    for (int r = 0; r < 4; ++r) {
        int row = m0 + mi * 16 + lg * 4 + r;
        int col = n0 + ni * 16 + lr;
        out[(size_t)row * HID_ + col] = acc[mi][ni][r] + bo[col];
    }
}

// ---------------- flash attention with rel-pos bias ----------------
// grid: (S/64, B*NH), block 256 (4 waves; wave w owns q-rows w*16..w*16+15)
__global__ __launch_bounds__(256) void k_flash(
    const unsigned short* __restrict__ Q, const unsigned short* __restrict__ K,
    const unsigned short* __restrict__ Vt,
    const float* __restrict__ rel_table, const float* __restrict__ mask,
    unsigned short* __restrict__ ctx)
{
    __shared__ unsigned short Qs[64 * 72];   // +8 pad: 16B-aligned rows, bank spread
    __shared__ unsigned short Ps[64 * 72];
    __shared__ float Ss[64 * 65];
    __shared__ float relc[TBL];
    __shared__ float facs[64];
    __shared__ float lsum[64];

    const int bh = blockIdx.y;
    const int b = bh >> 3, h = bh & 7;
    const int q0 = blockIdx.x * 64;
    const int t = threadIdx.x;
    const int lane = t & 63, w = t >> 6;
    const int lr = lane & 15, lg = lane >> 4;

    // stage Q tile (contiguous 64x64 in global)
    {
        const unsigned short* qg = &Q[((size_t)bh * S_ + q0) * HD_];
        int row = t >> 2, seg = t & 3;
        const u16x8* src = (const u16x8*)&qg[row * HD_ + seg * 16];
        u16x8* dst = (u16x8*)&Qs[row * 72 + seg * 16];
        dst[0] = src[0];
        dst[1] = src[1];
    }
    for (int i = t; i < TBL; i += 256) relc[i] = rel_table[i * NH_ + h];

    f4 cacc[4] = {};                 // ctx accum: 4 d-tiles of 16
    float m_j = -INFINITY, l_j = 0.f;

    __syncthreads();

    for (int kv0 = 0; kv0 < S_; kv0 += 64) {
        // ---- scores: S[64 q][64 k] via MFMA ----
        for (int nt = 0; nt < 4; ++nt) {
            f4 sacc = {};
            const int krow = kv0 + nt * 16 + lr;    // global key index (B-frag col)
            for (int kc = 0; kc < 2; ++kc) {
                bf8 a = *(const bf8*)&Qs[(w * 16 + lr) * 72 + kc * 32 + lg * 8];
                bf8 bb = *(const bf8*)&K[((size_t)bh * S_ + krow) * HD_ + kc * 32 + lg * 8];
                sacc = __builtin_amdgcn_mfma_f32_16x16x32_bf16(a, bb, sacc, 0, 0, 0);
            }
            const float mk = (1.0f - mask[b * S_ + krow]) * -3.4028235e38f;
            for (int r = 0; r < 4; ++r) {
                int qrow = w * 16 + lg * 4 + r;     // local q row
                int rel = krow - (q0 + qrow);
                rel = rel < -MAXREL ? -MAXREL : (rel > MAXREL ? MAXREL : rel);
                Ss[qrow * 65 + nt * 16 + lr] = sacc[r] * 0.125f + relc[rel + MAXREL] + mk;
            }
        }
        __syncthreads();
        // ---- online softmax: thread j owns row j (threads 0..63) ----
        if (t < 64) {
            const float* srow = &Ss[t * 65];
            float mx = m_j;
            for (int i = 0; i < 64; ++i) mx = fmaxf(mx, srow[i]);
            float fac = __expf(m_j - mx);
            float ls = l_j * fac;
            unsigned short* prow = &Ps[t * 72];
            for (int i = 0; i < 64; ++i) {
                float p = __expf(srow[i] - mx);
                ls += p;
                prow[i] = f2bf(p);
            }
            m_j = mx; l_j = ls;
            facs[t] = fac;
        }
        __syncthreads();
        // ---- rescale ctx + PV ----
        float fr[4];
        for (int r = 0; r < 4; ++r) fr[r] = facs[w * 16 + lg * 4 + r];
        for (int dt = 0; dt < 4; ++dt)
            for (int r = 0; r < 4; ++r) cacc[dt][r] *= fr[r];
        for (int dt = 0; dt < 4; ++dt) {
            for (int kc = 0; kc < 2; ++kc) {
                bf8 a = *(const bf8*)&Ps[(w * 16 + lr) * 72 + kc * 32 + lg * 8];
                bf8 bb = *(const bf8*)&Vt[((size_t)bh * HD_ + dt * 16 + lr) * S_ + kv0 + kc * 32 + lg * 8];
                cacc[dt] = __builtin_amdgcn_mfma_f32_16x16x32_bf16(a, bb, cacc[dt], 0, 0, 0);
            }
        }
    }
    if (t < 64) lsum[t] = l_j;
    __syncthreads();
    for (int dt = 0; dt < 4; ++dt) {
        for (int r = 0; r < 4; ++r) {
            int qrow = w * 16 + lg * 4 + r;
            float v = cacc[dt][r] / lsum[qrow];
            int tok = b * S_ + q0 + qrow;
            ctx[(size_t)tok * HID_ + h * HD_ + dt * 16 + lr] = f2bf(v);
        }
    }
}

// ---------------- launcher ----------------
extern "C" void kernel_launch(void* const* d_in, const int* in_sizes, int n_in,
                              void* d_out, int out_size, void* d_ws, size_t ws_size,
                              hipStream_t stream) {
    const float* hs  = (const float*)d_in[0];
    const float* msk = (const float*)d_in[1];
    const float* Wq  = (const float*)d_in[2];
    const float* bq  = (const float*)d_in[3];
    const float* Wk  = (const float*)d_in[4];
    const float* bk  = (const float*)d_in[5];
    const float* Wv  = (const float*)d_in[6];
    const float* bv  = (const float*)d_in[7];
    const float* Wo  = (const float*)d_in[8];
    const float* bo  = (const float*)d_in[9];
    const float* rel = (const float*)d_in[10];
    float* out = (float*)d_out;

    char* ws = (char*)d_ws;
    unsigned short* hsb = (unsigned short*)ws; ws += (size_t)M_ * HID_ * 2;
    unsigned short* Wqt = (unsigned short*)ws; ws += (size_t)HID_ * HID_ * 2;
    unsigned short* Wkt = (unsigned short*)ws; ws += (size_t)HID_ * HID_ * 2;
    unsigned short* Wvt = (unsigned short*)ws; ws += (size_t)HID_ * HID_ * 2;
    unsigned short* Wot = (unsigned short*)ws; ws += (size_t)HID_ * HID_ * 2;
    unsigned short* Qb  = (unsigned short*)ws; ws += (size_t)M_ * HID_ * 2;
    unsigned short* Kb  = (unsigned short*)ws; ws += (size_t)M_ * HID_ * 2;
    unsigned short* Vtb = (unsigned short*)ws; ws += (size_t)M_ * HID_ * 2;
    unsigned short* ctxb= (unsigned short*)ws; ws += (size_t)M_ * HID_ * 2;

    k_cast_hs<<<(M_ * HID_ / 4 + 255) / 256, 256, 0, stream>>>(hs, hsb, M_ * HID_ / 4);
    k_transpose_w<<<1024, 256, 0, stream>>>(Wq, Wqt);
    k_transpose_w<<<1024, 256, 0, stream>>>(Wk, Wkt);
    k_transpose_w<<<1024, 256, 0, stream>>>(Wv, Wvt);
    k_transpose_w<<<1024, 256, 0, stream>>>(Wo, Wot);
    k_gemm_qkv<<<dim3(M_ / 64, HID_ / 64, 3), 256, 0, stream>>>(
        hsb, Wqt, Wkt, Wvt, bq, bk, bv, Qb, Kb, Vtb);
    k_flash<<<dim3(S_ / 64, B_ * NH_), 256, 0, stream>>>(Qb, Kb, Vtb, rel, msk, ctxb);
    k_gemm_out<<<dim3(M_ / 64, HID_ / 64), 256, 0, stream>>>(ctxb, Wot, bo, out);
}

// Round 2
// 376.078 us; speedup vs baseline: 1.0409x; 1.0409x over previous
//
#include <hip/hip_runtime.h>
#include <hip/hip_bf16.h>

#define B_    4
#define S_    2048
#define HID_  512
#define NH_   8
#define HD_   64
#define MAXREL 512
#define TBL   1025
#define M_    (B_ * S_)   // 8192 tokens

typedef __attribute__((ext_vector_type(8))) short bf8;            // 8 bf16 (MFMA A/B frag)
typedef __attribute__((ext_vector_type(4))) float f4;             // MFMA C/D frag

static __device__ __forceinline__ unsigned short f2bf(float f) {
    union { float f; unsigned int u; } v; v.f = f;
    unsigned int u = v.u;
    unsigned int r = (u + 0x7FFFu + ((u >> 16) & 1u)) >> 16;   // round-nearest-even
    return (unsigned short)r;
}

// ---------------- cast hidden_states fp32 -> bf16 ----------------
__global__ void k_cast_hs(const float* __restrict__ src, unsigned short* __restrict__ dst, int n4) {
    int i = blockIdx.x * blockDim.x + threadIdx.x;
    if (i >= n4) return;
    float4 v = ((const float4*)src)[i];
    ushort4 o;
    o.x = f2bf(v.x); o.y = f2bf(v.y); o.z = f2bf(v.z); o.w = f2bf(v.w);
    ((ushort4*)dst)[i] = o;
}

// ---------------- transpose + cast weight: Wt[n][k] = bf16(W[k][n]) ----------------
__global__ void k_transpose_w(const float* __restrict__ W, unsigned short* __restrict__ Wt) {
    int t = blockIdx.x * blockDim.x + threadIdx.x;   // 512*512
    int n = t >> 9, k = t & 511;
    Wt[t] = f2bf(W[k * HID_ + n]);
    (void)n;
}

// ---------------- QKV projection GEMM (bf16 MFMA, fp32 accum) ----------------
__global__ __launch_bounds__(256) void k_gemm_qkv(
    const unsigned short* __restrict__ Abf,
    const unsigned short* __restrict__ Wqt, const unsigned short* __restrict__ Wkt,
    const unsigned short* __restrict__ Wvt,
    const float* __restrict__ bq, const float* __restrict__ bk, const float* __restrict__ bv,
    unsigned short* __restrict__ Q, unsigned short* __restrict__ K, unsigned short* __restrict__ Vt)
{
    const int z = blockIdx.z;
    const unsigned short* Wt = (z == 0) ? Wqt : ((z == 1) ? Wkt : Wvt);
    const float* bias = (z == 0) ? bq : ((z == 1) ? bk : bv);
    const int lane = threadIdx.x & 63, w = threadIdx.x >> 6;
    const int wr = w >> 1, wc = w & 1;
    const int m0 = blockIdx.x * 64 + wr * 32;
    const int n0 = blockIdx.y * 64 + wc * 32;
    const int lr = lane & 15, lg = lane >> 4;

    f4 acc[2][2] = {};
    for (int k0 = 0; k0 < HID_; k0 += 32) {
        const int kk = k0 + lg * 8;
        bf8 a0 = *(const bf8*)&Abf[(size_t)(m0 + lr) * HID_ + kk];
        bf8 a1 = *(const bf8*)&Abf[(size_t)(m0 + 16 + lr) * HID_ + kk];
        bf8 b0 = *(const bf8*)&Wt[(size_t)(n0 + lr) * HID_ + kk];
        bf8 b1 = *(const bf8*)&Wt[(size_t)(n0 + 16 + lr) * HID_ + kk];
        acc[0][0] = __builtin_amdgcn_mfma_f32_16x16x32_bf16(a0, b0, acc[0][0], 0, 0, 0);
        acc[0][1] = __builtin_amdgcn_mfma_f32_16x16x32_bf16(a0, b1, acc[0][1], 0, 0, 0);
        acc[1][0] = __builtin_amdgcn_mfma_f32_16x16x32_bf16(a1, b0, acc[1][0], 0, 0, 0);
        acc[1][1] = __builtin_amdgcn_mfma_f32_16x16x32_bf16(a1, b1, acc[1][1], 0, 0, 0);
    }
    for (int mi = 0; mi < 2; ++mi)
    for (int ni = 0; ni < 2; ++ni)
    for (int r = 0; r < 4; ++r) {
        int row = m0 + mi * 16 + lg * 4 + r;     // token
        int col = n0 + ni * 16 + lr;             // hid
        float v = acc[mi][ni][r] + bias[col];
        unsigned short bf = f2bf(v);
        int b = row >> 11, s = row & 2047;
        int h = col >> 6, d = col & 63;
        if (z == 2) {
            Vt[(((size_t)(b * NH_ + h)) * HD_ + d) * S_ + s] = bf;
        } else {
            unsigned short* dst = (z == 0) ? Q : K;
            dst[(((size_t)(b * NH_ + h)) * S_ + s) * HD_ + d] = bf;
        }
    }
}

// ---------------- output projection GEMM: out fp32 [8192,512] ----------------
__global__ __launch_bounds__(256) void k_gemm_out(
    const unsigned short* __restrict__ Abf,
    const unsigned short* __restrict__ Wot,
    const float* __restrict__ bo,
    float* __restrict__ out)
{
    const int lane = threadIdx.x & 63, w = threadIdx.x >> 6;
    const int wr = w >> 1, wc = w & 1;
    const int m0 = blockIdx.x * 64 + wr * 32;
    const int n0 = blockIdx.y * 64 + wc * 32;
    const int lr = lane & 15, lg = lane >> 4;

    f4 acc[2][2] = {};
    for (int k0 = 0; k0 < HID_; k0 += 32) {
        const int kk = k0 + lg * 8;
        bf8 a0 = *(const bf8*)&Abf[(size_t)(m0 + lr) * HID_ + kk];
        bf8 a1 = *(const bf8*)&Abf[(size_t)(m0 + 16 + lr) * HID_ + kk];
        bf8 b0 = *(const bf8*)&Wot[(size_t)(n0 + lr) * HID_ + kk];
        bf8 b1 = *(const bf8*)&Wot[(size_t)(n0 + 16 + lr) * HID_ + kk];
        acc[0][0] = __builtin_amdgcn_mfma_f32_16x16x32_bf16(a0, b0, acc[0][0], 0, 0, 0);
        acc[0][1] = __builtin_amdgcn_mfma_f32_16x16x32_bf16(a0, b1, acc[0][1], 0, 0, 0);
        acc[1][0] = __builtin_amdgcn_mfma_f32_16x16x32_bf16(a1, b0, acc[1][0], 0, 0, 0);
        acc[1][1] = __builtin_amdgcn_mfma_f32_16x16x32_bf16(a1, b1, acc[1][1], 0, 0, 0);
    }
    for (int mi = 0; mi < 2; ++mi)
    for (int ni = 0; ni < 2; ++ni)
    for (int r = 0; r < 4; ++r) {
        int row = m0 + mi * 16 + lg * 4 + r;
        int col = n0 + ni * 16 + lr;
        out[(size_t)row * HID_ + col] = acc[mi][ni][r] + bo[col];
    }
}

// ---------------- flash attention, swapped operands, register softmax ----------------
// grid: 1024 blocks (XCD-swizzled to (bh, q-block)), block 256 = 4 independent waves.
// Wave w owns q rows [q0+w*16, q0+w*16+16). Swapped QK^T: lane holds q=lane&15,
// keys nt*16+lg*4+r -> softmax is lane-local + 2 shfl_xor. No barriers in kv loop.
__global__ __launch_bounds__(256) void k_flash(
    const unsigned short* __restrict__ Q, const unsigned short* __restrict__ K,
    const unsigned short* __restrict__ Vt,
    const float* __restrict__ rel_table, const float* __restrict__ mask,
    unsigned short* __restrict__ ctx)
{
    __shared__ unsigned short Ps[4][16][72];   // wave-private P tile, 72-pad (16B rows, bank spread)
    __shared__ float relc[TBL];
    __shared__ float maskc[S_];

    const int t = threadIdx.x;
    // bijective XCD swizzle: each XCD owns 4 complete (b,h) pairs (K+V = 2MB, L2-fits)
    const int flat = blockIdx.y * gridDim.x + blockIdx.x;   // 0..1023, dispatch order
    const int bh = (flat & 7) * 4 + ((flat >> 3) >> 5);
    const int qb = (flat >> 3) & 31;
    const int b = bh >> 3, h = bh & 7;
    const int q0 = qb * 64;
    const int lane = t & 63, w = t >> 6;
    const int lr = lane & 15, lg = lane >> 4;

    for (int i = t; i < TBL; i += 256) relc[i] = rel_table[i * NH_ + h];
    for (int i = t; i < S_; i += 256)
        maskc[i] = (1.0f - mask[b * S_ + i]) * -3.4028235e38f;

    // Q B-fragment (col=q=lr, k=d) hoisted to registers
    const int myq = q0 + w * 16 + lr;
    bf8 qf0, qf1;
    {
        const unsigned short* qg = &Q[((size_t)bh * S_ + myq) * HD_ + lg * 8];
        qf0 = *(const bf8*)qg;
        qf1 = *(const bf8*)(qg + 32);
    }

    f4 cacc[4] = {};          // ctx^T accum: lane holds q=lr, d=dt*16+lg*4+r
    float m_s = -INFINITY, l_s = 0.f;

    __syncthreads();

    const unsigned short* Kb = &K[(size_t)bh * S_ * HD_];
    const unsigned short* Vb = &Vt[(size_t)bh * HD_ * S_];

    for (int kv0 = 0; kv0 < S_; kv0 += 64) {
        // ---- scores^T: S[key][q] via mfma(K, Q) ----
        f4 sacc[4];
        for (int nt = 0; nt < 4; ++nt) {
            const unsigned short* kg = &Kb[(size_t)(kv0 + nt * 16 + lr) * HD_ + lg * 8];
            f4 s = {};
            s = __builtin_amdgcn_mfma_f32_16x16x32_bf16(*(const bf8*)kg, qf0, s, 0, 0, 0);
            s = __builtin_amdgcn_mfma_f32_16x16x32_bf16(*(const bf8*)(kg + 32), qf1, s, 0, 0, 0);
            sacc[nt] = s;
        }
        // ---- bias + mask + running max (lane-local: 16 keys of row q=myq) ----
        float mnew = m_s;
        for (int nt = 0; nt < 4; ++nt)
            for (int r = 0; r < 4; ++r) {
                int key = kv0 + nt * 16 + lg * 4 + r;
                int rel = key - myq;
                rel = rel < -MAXREL ? -MAXREL : (rel > MAXREL ? MAXREL : rel);
                float sv = sacc[nt][r] * 0.125f + relc[rel + MAXREL] + maskc[key];
                sacc[nt][r] = sv;
                mnew = fmaxf(mnew, sv);
            }
        mnew = fmaxf(mnew, __shfl_xor(mnew, 16));
        mnew = fmaxf(mnew, __shfl_xor(mnew, 32));

        const float fac = __expf(m_s - mnew);
        float psum = 0.f;
        unsigned int pk[8];
        for (int nt = 0; nt < 4; ++nt) {
            float p0 = __expf(sacc[nt][0] - mnew);
            float p1 = __expf(sacc[nt][1] - mnew);
            float p2 = __expf(sacc[nt][2] - mnew);
            float p3 = __expf(sacc[nt][3] - mnew);
            psum += (p0 + p1) + (p2 + p3);
            asm("v_cvt_pk_bf16_f32 %0, %1, %2" : "=v"(pk[nt * 2])     : "v"(p0), "v"(p1));
            asm("v_cvt_pk_bf16_f32 %0, %1, %2" : "=v"(pk[nt * 2 + 1]) : "v"(p2), "v"(p3));
        }
        psum += __shfl_xor(psum, 16);
        psum += __shfl_xor(psum, 32);
        l_s = l_s * fac + psum;
        m_s = mnew;
        for (int dt = 0; dt < 4; ++dt)
            for (int r = 0; r < 4; ++r) cacc[dt][r] *= fac;

        // ---- wave-local P transpose: write [q=lr][key], 4 consecutive keys per store ----
        for (int nt = 0; nt < 4; ++nt) {
            uint2 pv; pv.x = pk[nt * 2]; pv.y = pk[nt * 2 + 1];
            *(uint2*)&Ps[w][lr][nt * 16 + lg * 4] = pv;
        }
        // same-wave ds_write -> ds_read fence (rule #18: keep compiler from reordering)
        asm volatile("s_waitcnt lgkmcnt(0)" ::: "memory");
        __builtin_amdgcn_sched_barrier(0);

        // ---- PV (swapped): ctx^T += mfma(V^T, P) ----
        for (int kc = 0; kc < 2; ++kc) {
            bf8 pb = *(const bf8*)&Ps[w][lr][kc * 32 + lg * 8];
            for (int dt = 0; dt < 4; ++dt) {
                const unsigned short* vg = &Vb[(size_t)(dt * 16 + lr) * S_ + kv0 + kc * 32 + lg * 8];
                cacc[dt] = __builtin_amdgcn_mfma_f32_16x16x32_bf16(*(const bf8*)vg, pb, cacc[dt], 0, 0, 0);
            }
        }
        __builtin_amdgcn_sched_barrier(0);   // keep next tile's P-write after these reads
    }

    // ---- epilogue: divide by l, write ctx (4 bf16 = 8B per store, d-contiguous) ----
    const float inv = 1.0f / l_s;
    unsigned short* cg = &ctx[(size_t)(b * S_ + myq) * HID_ + h * HD_];
    for (int dt = 0; dt < 4; ++dt) {
        ushort4 o;
        o.x = f2bf(cacc[dt][0] * inv);
        o.y = f2bf(cacc[dt][1] * inv);
        o.z = f2bf(cacc[dt][2] * inv);
        o.w = f2bf(cacc[dt][3] * inv);
        *(ushort4*)&cg[dt * 16 + lg * 4] = o;
    }
}

// ---------------- launcher ----------------
extern "C" void kernel_launch(void* const* d_in, const int* in_sizes, int n_in,
                              void* d_out, int out_size, void* d_ws, size_t ws_size,
                              hipStream_t stream) {
    const float* hs  = (const float*)d_in[0];
    const float* msk = (const float*)d_in[1];
    const float* Wq  = (const float*)d_in[2];
    const float* bq  = (const float*)d_in[3];
    const float* Wk  = (const float*)d_in[4];
    const float* bk  = (const float*)d_in[5];
    const float* Wv  = (const float*)d_in[6];
    const float* bv  = (const float*)d_in[7];
    const float* Wo  = (const float*)d_in[8];
    const float* bo  = (const float*)d_in[9];
    const float* rel = (const float*)d_in[10];
    float* out = (float*)d_out;

    char* ws = (char*)d_ws;
    unsigned short* hsb = (unsigned short*)ws; ws += (size_t)M_ * HID_ * 2;
    unsigned short* Wqt = (unsigned short*)ws; ws += (size_t)HID_ * HID_ * 2;
    unsigned short* Wkt = (unsigned short*)ws; ws += (size_t)HID_ * HID_ * 2;
    unsigned short* Wvt = (unsigned short*)ws; ws += (size_t)HID_ * HID_ * 2;
    unsigned short* Wot = (unsigned short*)ws; ws += (size_t)HID_ * HID_ * 2;
    unsigned short* Qb  = (unsigned short*)ws; ws += (size_t)M_ * HID_ * 2;
    unsigned short* Kb  = (unsigned short*)ws; ws += (size_t)M_ * HID_ * 2;
    unsigned short* Vtb = (unsigned short*)ws; ws += (size_t)M_ * HID_ * 2;
    unsigned short* ctxb= (unsigned short*)ws; ws += (size_t)M_ * HID_ * 2;

    k_cast_hs<<<(M_ * HID_ / 4 + 255) / 256, 256, 0, stream>>>(hs, hsb, M_ * HID_ / 4);
    k_transpose_w<<<1024, 256, 0, stream>>>(Wq, Wqt);
    k_transpose_w<<<1024, 256, 0, stream>>>(Wk, Wkt);
    k_transpose_w<<<1024, 256, 0, stream>>>(Wv, Wvt);
    k_transpose_w<<<1024, 256, 0, stream>>>(Wo, Wot);
    k_gemm_qkv<<<dim3(M_ / 64, HID_ / 64, 3), 256, 0, stream>>>(
        hsb, Wqt, Wkt, Wvt, bq, bk, bv, Qb, Kb, Vtb);
    k_flash<<<dim3(S_ / 64, B_ * NH_), 256, 0, stream>>>(Qb, Kb, Vtb, rel, msk, ctxb);
    k_gemm_out<<<dim3(M_ / 64, HID_ / 64), 256, 0, stream>>>(ctxb, Wot, bo, out);
}

// Round 3
// 372.152 us; speedup vs baseline: 1.0519x; 1.0105x over previous
//
#include <hip/hip_runtime.h>
#include <hip/hip_bf16.h>

#define B_    4
#define S_    2048
#define HID_  512
#define NH_   8
#define HD_   64
#define MAXREL 512
#define M_    (B_ * S_)   // 8192 tokens

#define LOG2E 1.44269504f
#define SCALE_Q (0.125f * LOG2E)   // folded into Q at projection time

typedef __attribute__((ext_vector_type(8))) short bf8;            // 8 bf16 (MFMA A/B frag)
typedef __attribute__((ext_vector_type(4))) float f4;             // MFMA C/D frag

static __device__ __forceinline__ unsigned short f2bf(float f) {
    union { float f; unsigned int u; } v; v.f = f;
    unsigned int u = v.u;
    unsigned int r = (u + 0x7FFFu + ((u >> 16) & 1u)) >> 16;   // round-nearest-even
    return (unsigned short)r;
}

static __device__ __forceinline__ float ex2(float x) {   // raw v_exp_f32 (base-2)
    float r; asm("v_exp_f32 %0, %1" : "=v"(r) : "v"(x)); return r;
}

// ---------------- cast hidden_states fp32 -> bf16 ----------------
__global__ void k_cast_hs(const float* __restrict__ src, unsigned short* __restrict__ dst, int n4) {
    int i = blockIdx.x * blockDim.x + threadIdx.x;
    if (i >= n4) return;
    float4 v = ((const float4*)src)[i];
    ushort4 o;
    o.x = f2bf(v.x); o.y = f2bf(v.y); o.z = f2bf(v.z); o.w = f2bf(v.w);
    ((ushort4*)dst)[i] = o;
}

// ---------------- transpose + cast 4 weights in one launch ----------------
__global__ void k_transpose_w4(const float* __restrict__ W0, const float* __restrict__ W1,
                               const float* __restrict__ W2, const float* __restrict__ W3,
                               unsigned short* __restrict__ T0, unsigned short* __restrict__ T1,
                               unsigned short* __restrict__ T2, unsigned short* __restrict__ T3) {
    const int z = blockIdx.y;
    const float* W = (z == 0) ? W0 : (z == 1) ? W1 : (z == 2) ? W2 : W3;
    unsigned short* T = (z == 0) ? T0 : (z == 1) ? T1 : (z == 2) ? T2 : T3;
    int t = blockIdx.x * blockDim.x + threadIdx.x;   // 512*512
    int k = t & 511;
    T[t] = f2bf(W[k * HID_ + (t >> 9)]);
}

// ---------------- QKV projection GEMM (bf16 MFMA, fp32 accum) ----------------
//   z=0: Q[b,h,s,d] (pre-scaled by 0.125*log2e)  z=1: K[b,h,s,d]  z=2: Vt[b,h,d,s]
__global__ __launch_bounds__(256) void k_gemm_qkv(
    const unsigned short* __restrict__ Abf,
    const unsigned short* __restrict__ Wqt, const unsigned short* __restrict__ Wkt,
    const unsigned short* __restrict__ Wvt,
    const float* __restrict__ bq, const float* __restrict__ bk, const float* __restrict__ bv,
    unsigned short* __restrict__ Q, unsigned short* __restrict__ K, unsigned short* __restrict__ Vt)
{
    const int z = blockIdx.z;
    const unsigned short* Wt = (z == 0) ? Wqt : ((z == 1) ? Wkt : Wvt);
    const float* bias = (z == 0) ? bq : ((z == 1) ? bk : bv);
    const float osc = (z == 0) ? SCALE_Q : 1.0f;
    const int lane = threadIdx.x & 63, w = threadIdx.x >> 6;
    const int wr = w >> 1, wc = w & 1;
    const int m0 = blockIdx.x * 64 + wr * 32;
    const int n0 = blockIdx.y * 64 + wc * 32;
    const int lr = lane & 15, lg = lane >> 4;

    f4 acc[2][2] = {};
    for (int k0 = 0; k0 < HID_; k0 += 32) {
        const int kk = k0 + lg * 8;
        bf8 a0 = *(const bf8*)&Abf[(size_t)(m0 + lr) * HID_ + kk];
        bf8 a1 = *(const bf8*)&Abf[(size_t)(m0 + 16 + lr) * HID_ + kk];
        bf8 b0 = *(const bf8*)&Wt[(size_t)(n0 + lr) * HID_ + kk];
        bf8 b1 = *(const bf8*)&Wt[(size_t)(n0 + 16 + lr) * HID_ + kk];
        acc[0][0] = __builtin_amdgcn_mfma_f32_16x16x32_bf16(a0, b0, acc[0][0], 0, 0, 0);
        acc[0][1] = __builtin_amdgcn_mfma_f32_16x16x32_bf16(a0, b1, acc[0][1], 0, 0, 0);
        acc[1][0] = __builtin_amdgcn_mfma_f32_16x16x32_bf16(a1, b0, acc[1][0], 0, 0, 0);
        acc[1][1] = __builtin_amdgcn_mfma_f32_16x16x32_bf16(a1, b1, acc[1][1], 0, 0, 0);
    }
    for (int mi = 0; mi < 2; ++mi)
    for (int ni = 0; ni < 2; ++ni)
    for (int r = 0; r < 4; ++r) {
        int row = m0 + mi * 16 + lg * 4 + r;     // token
        int col = n0 + ni * 16 + lr;             // hid
        float v = (acc[mi][ni][r] + bias[col]) * osc;
        unsigned short bf = f2bf(v);
        int b = row >> 11, s = row & 2047;
        int h = col >> 6, d = col & 63;
        if (z == 2) {
            Vt[(((size_t)(b * NH_ + h)) * HD_ + d) * S_ + s] = bf;
        } else {
            unsigned short* dst = (z == 0) ? Q : K;
            dst[(((size_t)(b * NH_ + h)) * S_ + s) * HD_ + d] = bf;
        }
    }
}

// ---------------- output projection GEMM: out fp32 [8192,512] ----------------
__global__ __launch_bounds__(256) void k_gemm_out(
    const unsigned short* __restrict__ Abf,
    const unsigned short* __restrict__ Wot,
    const float* __restrict__ bo,
    float* __restrict__ out)
{
    const int lane = threadIdx.x & 63, w = threadIdx.x >> 6;
    const int wr = w >> 1, wc = w & 1;
    const int m0 = blockIdx.x * 64 + wr * 32;
    const int n0 = blockIdx.y * 64 + wc * 32;
    const int lr = lane & 15, lg = lane >> 4;

    f4 acc[2][2] = {};
    for (int k0 = 0; k0 < HID_; k0 += 32) {
        const int kk = k0 + lg * 8;
        bf8 a0 = *(const bf8*)&Abf[(size_t)(m0 + lr) * HID_ + kk];
        bf8 a1 = *(const bf8*)&Abf[(size_t)(m0 + 16 + lr) * HID_ + kk];
        bf8 b0 = *(const bf8*)&Wot[(size_t)(n0 + lr) * HID_ + kk];
        bf8 b1 = *(const bf8*)&Wot[(size_t)(n0 + 16 + lr) * HID_ + kk];
        acc[0][0] = __builtin_amdgcn_mfma_f32_16x16x32_bf16(a0, b0, acc[0][0], 0, 0, 0);
        acc[0][1] = __builtin_amdgcn_mfma_f32_16x16x32_bf16(a0, b1, acc[0][1], 0, 0, 0);
        acc[1][0] = __builtin_amdgcn_mfma_f32_16x16x32_bf16(a1, b0, acc[1][0], 0, 0, 0);
        acc[1][1] = __builtin_amdgcn_mfma_f32_16x16x32_bf16(a1, b1, acc[1][1], 0, 0, 0);
    }
    for (int mi = 0; mi < 2; ++mi)
    for (int ni = 0; ni < 2; ++ni)
    for (int r = 0; r < 4; ++r) {
        int row = m0 + mi * 16 + lg * 4 + r;
        int col = n0 + ni * 16 + lr;
        out[(size_t)row * HID_ + col] = acc[mi][ni][r] + bo[col];
    }
}

// ---------------- flash attention: swapped operands, register softmax,
//                  K double-buffered in regs, V early-issued ----------------
// 1024 blocks (XCD-swizzled), 4 independent waves/block, no barriers in kv loop.
// Wave w owns q rows [q0+w*16, +16). Scores in base-2 domain (scales folded).
__global__ __launch_bounds__(256, 3) void k_flash(
    const unsigned short* __restrict__ Q, const unsigned short* __restrict__ K,
    const unsigned short* __restrict__ Vt,
    const float* __restrict__ rel_table, const float* __restrict__ mask,
    unsigned short* __restrict__ ctx)
{
    __shared__ unsigned short Ps[4][16][72];   // wave-private P tile
    __shared__ float Tp[2112];                 // pre-clipped bias window * log2e
    __shared__ float maskc[S_];

    const int t = threadIdx.x;
    // bijective XCD swizzle: each XCD owns 4 complete (b,h) pairs (K+V L2-fit)
    const int flat = blockIdx.y * gridDim.x + blockIdx.x;   // 0..1023
    const int bh = (flat & 7) * 4 + ((flat >> 3) >> 5);
    const int qb = (flat >> 3) & 31;
    const int b = bh >> 3, h = bh & 7;
    const int q0 = qb * 64;
    const int lane = t & 63, w = t >> 6;
    const int lr = lane & 15, lg = lane >> 4;

    // bias window: Tp[i] = log2e * rel_clip(i - 63 - q0), i in [0,2112)
    for (int i = t; i < 2112; i += 256) {
        int j = i - 63 - q0;
        j = j < -MAXREL ? -MAXREL : (j > MAXREL ? MAXREL : j);
        Tp[i] = rel_table[(j + MAXREL) * NH_ + h] * LOG2E;
    }
    for (int i = t; i < S_; i += 256)
        maskc[i] = (1.0f - mask[b * S_ + i]) * -3.0e38f;   // absorbs scores, matches ref

    const int myq = q0 + w * 16 + lr;
    bf8 qf0, qf1;   // Q B-frag (pre-scaled by 0.125*log2e at projection)
    {
        const unsigned short* qg = &Q[((size_t)bh * S_ + myq) * HD_ + lg * 8];
        qf0 = *(const bf8*)qg;
        qf1 = *(const bf8*)(qg + 32);
    }

    f4 cacc[4] = {};          // ctx^T accum: lane holds q=lr, d=dt*16+lg*4+r
    float m_s = -INFINITY, l_s = 0.f;

    __syncthreads();

    const unsigned short* Kb = &K[(size_t)bh * S_ * HD_];
    const unsigned short* Vb = &Vt[(size_t)bh * HD_ * S_];
    const int ib0 = 63 + lg * 4 - w * 16 - lr;   // Tp base (add kv0 + nt*16 + r)

#define LOADK(dst, base_) { \
    _Pragma("unroll") \
    for (int nt_ = 0; nt_ < 4; ++nt_) { \
        const unsigned short* kg_ = &Kb[(size_t)((base_) + nt_ * 16 + lr) * HD_ + lg * 8]; \
        dst[nt_ * 2]     = *(const bf8*)kg_; \
        dst[nt_ * 2 + 1] = *(const bf8*)(kg_ + 32); \
    } }

    auto body = [&](const bf8* kf, int kv0) {
        // early-issue V loads (used after softmax, ~400cy later)
        bf8 vf[8];
        #pragma unroll
        for (int kc = 0; kc < 2; ++kc)
            #pragma unroll
            for (int dt = 0; dt < 4; ++dt)
                vf[kc * 4 + dt] = *(const bf8*)&Vb[(size_t)(dt * 16 + lr) * S_ + kv0 + kc * 32 + lg * 8];

        // scores^T: S[key][q] = mfma(K, Q); lane holds q=lr, keys nt*16+lg*4+r
        f4 sacc[4];
        #pragma unroll
        for (int nt = 0; nt < 4; ++nt) {
            f4 s = {};
            s = __builtin_amdgcn_mfma_f32_16x16x32_bf16(kf[nt * 2],     qf0, s, 0, 0, 0);
            s = __builtin_amdgcn_mfma_f32_16x16x32_bf16(kf[nt * 2 + 1], qf1, s, 0, 0, 0);
            sacc[nt] = s;
        }
        // bias + mask + running max (all base-2 domain)
        float mnew = m_s;
        #pragma unroll
        for (int nt = 0; nt < 4; ++nt) {
            const float4 mk4 = *(const float4*)&maskc[kv0 + nt * 16 + lg * 4];
            const int ibn = ib0 + kv0 + nt * 16;
            #pragma unroll
            for (int r = 0; r < 4; ++r) {
                float mkv = (r == 0) ? mk4.x : (r == 1) ? mk4.y : (r == 2) ? mk4.z : mk4.w;
                float sv = sacc[nt][r] + Tp[ibn + r] + mkv;
                sacc[nt][r] = sv;
                mnew = fmaxf(mnew, sv);
            }
        }
        mnew = fmaxf(mnew, __shfl_xor(mnew, 16));
        mnew = fmaxf(mnew, __shfl_xor(mnew, 32));

        const float fac = ex2(m_s - mnew);
        float psum = 0.f;
        unsigned int pk[8];
        #pragma unroll
        for (int nt = 0; nt < 4; ++nt) {
            float p0 = ex2(sacc[nt][0] - mnew);
            float p1 = ex2(sacc[nt][1] - mnew);
            float p2 = ex2(sacc[nt][2] - mnew);
            float p3 = ex2(sacc[nt][3] - mnew);
            psum += (p0 + p1) + (p2 + p3);
            asm("v_cvt_pk_bf16_f32 %0, %1, %2" : "=v"(pk[nt * 2])     : "v"(p0), "v"(p1));
            asm("v_cvt_pk_bf16_f32 %0, %1, %2" : "=v"(pk[nt * 2 + 1]) : "v"(p2), "v"(p3));
        }
        psum += __shfl_xor(psum, 16);
        psum += __shfl_xor(psum, 32);
        l_s = l_s * fac + psum;
        m_s = mnew;
        #pragma unroll
        for (int dt = 0; dt < 4; ++dt)
            #pragma unroll
            for (int r = 0; r < 4; ++r) cacc[dt][r] *= fac;

        // wave-local P transpose through LDS
        #pragma unroll
        for (int nt = 0; nt < 4; ++nt) {
            uint2 pv; pv.x = pk[nt * 2]; pv.y = pk[nt * 2 + 1];
            *(uint2*)&Ps[w][lr][nt * 16 + lg * 4] = pv;
        }
        asm volatile("s_waitcnt lgkmcnt(0)" ::: "memory");
        __builtin_amdgcn_sched_barrier(0);

        // PV (swapped): ctx^T += mfma(V^T, P)
        #pragma unroll
        for (int kc = 0; kc < 2; ++kc) {
            bf8 pb = *(const bf8*)&Ps[w][lr][kc * 32 + lg * 8];
            #pragma unroll
            for (int dt = 0; dt < 4; ++dt)
                cacc[dt] = __builtin_amdgcn_mfma_f32_16x16x32_bf16(vf[kc * 4 + dt], pb, cacc[dt], 0, 0, 0);
        }
    };

    bf8 ka[8], kb_[8];
    LOADK(ka, 0);
    for (int kv0 = 0; kv0 < S_; kv0 += 128) {
        LOADK(kb_, kv0 + 64);                 // prefetch tile t+1
        body(ka, kv0);
        const int kvn = (kv0 + 128 < S_) ? (kv0 + 128) : (kv0 + 64);
        LOADK(ka, kvn);                       // prefetch tile t+2 (clamped at end)
        body(kb_, kv0 + 64);
    }
#undef LOADK

    // epilogue: divide by l, write ctx (8B stores, d-contiguous)
    const float inv = 1.0f / l_s;
    unsigned short* cg = &ctx[(size_t)(b * S_ + myq) * HID_ + h * HD_];
    #pragma unroll
    for (int dt = 0; dt < 4; ++dt) {
        ushort4 o;
        o.x = f2bf(cacc[dt][0] * inv);
        o.y = f2bf(cacc[dt][1] * inv);
        o.z = f2bf(cacc[dt][2] * inv);
        o.w = f2bf(cacc[dt][3] * inv);
        *(ushort4*)&cg[dt * 16 + lg * 4] = o;
    }
}

// ---------------- launcher ----------------
extern "C" void kernel_launch(void* const* d_in, const int* in_sizes, int n_in,
                              void* d_out, int out_size, void* d_ws, size_t ws_size,
                              hipStream_t stream) {
    const float* hs  = (const float*)d_in[0];
    const float* msk = (const float*)d_in[1];
    const float* Wq  = (const float*)d_in[2];
    const float* bq  = (const float*)d_in[3];
    const float* Wk  = (const float*)d_in[4];
    const float* bk  = (const float*)d_in[5];
    const float* Wv  = (const float*)d_in[6];
    const float* bv  = (const float*)d_in[7];
    const float* Wo  = (const float*)d_in[8];
    const float* bo  = (const float*)d_in[9];
    const float* rel = (const float*)d_in[10];
    float* out = (float*)d_out;

    char* ws = (char*)d_ws;
    unsigned short* hsb = (unsigned short*)ws; ws += (size_t)M_ * HID_ * 2;
    unsigned short* Wqt = (unsigned short*)ws; ws += (size_t)HID_ * HID_ * 2;
    unsigned short* Wkt = (unsigned short*)ws; ws += (size_t)HID_ * HID_ * 2;
    unsigned short* Wvt = (unsigned short*)ws; ws += (size_t)HID_ * HID_ * 2;
    unsigned short* Wot = (unsigned short*)ws; ws += (size_t)HID_ * HID_ * 2;
    unsigned short* Qb  = (unsigned short*)ws; ws += (size_t)M_ * HID_ * 2;
    unsigned short* Kb  = (unsigned short*)ws; ws += (size_t)M_ * HID_ * 2;
    unsigned short* Vtb = (unsigned short*)ws; ws += (size_t)M_ * HID_ * 2;
    unsigned short* ctxb= (unsigned short*)ws; ws += (size_t)M_ * HID_ * 2;

    k_cast_hs<<<(M_ * HID_ / 4 + 255) / 256, 256, 0, stream>>>(hs, hsb, M_ * HID_ / 4);
    k_transpose_w4<<<dim3(1024, 4), 256, 0, stream>>>(Wq, Wk, Wv, Wo, Wqt, Wkt, Wvt, Wot);
    k_gemm_qkv<<<dim3(M_ / 64, HID_ / 64, 3), 256, 0, stream>>>(
        hsb, Wqt, Wkt, Wvt, bq, bk, bv, Qb, Kb, Vtb);
    k_flash<<<dim3(S_ / 64, B_ * NH_), 256, 0, stream>>>(Qb, Kb, Vtb, rel, msk, ctxb);
    k_gemm_out<<<dim3(M_ / 64, HID_ / 64), 256, 0, stream>>>(ctxb, Wot, bo, out);
}

// Round 4
// 223.844 us; speedup vs baseline: 1.7489x; 1.6625x over previous
//
#include <hip/hip_runtime.h>
#include <hip/hip_bf16.h>

#define B_    4
#define S_    2048
#define HID_  512
#define NH_   8
#define HD_   64
#define MAXREL 512
#define M_    (B_ * S_)   // 8192 tokens

#define LOG2E 1.44269504f
#define SCALE_Q (0.125f * LOG2E)   // folded into Q at projection time

typedef __attribute__((ext_vector_type(8))) short bf8;            // 8 bf16 (MFMA A/B frag)
typedef __attribute__((ext_vector_type(4))) float f4;             // MFMA C/D frag

static __device__ __forceinline__ unsigned short f2bf(float f) {
    union { float f; unsigned int u; } v; v.f = f;
    unsigned int u = v.u;
    unsigned int r = (u + 0x7FFFu + ((u >> 16) & 1u)) >> 16;   // round-nearest-even
    return (unsigned short)r;
}

static __device__ __forceinline__ float ex2(float x) {   // raw v_exp_f32 (base-2)
    float r; asm("v_exp_f32 %0, %1" : "=v"(r) : "v"(x)); return r;
}

#define MFMA16(a, b, c) __builtin_amdgcn_mfma_f32_16x16x32_bf16((a), (b), (c), 0, 0, 0)

// ---------------- cast hidden_states fp32 -> bf16 ----------------
__global__ void k_cast_hs(const float* __restrict__ src, unsigned short* __restrict__ dst, int n4) {
    int i = blockIdx.x * blockDim.x + threadIdx.x;
    if (i >= n4) return;
    float4 v = ((const float4*)src)[i];
    ushort4 o;
    o.x = f2bf(v.x); o.y = f2bf(v.y); o.z = f2bf(v.z); o.w = f2bf(v.w);
    ((ushort4*)dst)[i] = o;
}

// ---------------- transpose + cast 4 weights in one launch ----------------
__global__ void k_transpose_w4(const float* __restrict__ W0, const float* __restrict__ W1,
                               const float* __restrict__ W2, const float* __restrict__ W3,
                               unsigned short* __restrict__ T0, unsigned short* __restrict__ T1,
                               unsigned short* __restrict__ T2, unsigned short* __restrict__ T3) {
    const int z = blockIdx.y;
    const float* W = (z == 0) ? W0 : (z == 1) ? W1 : (z == 2) ? W2 : W3;
    unsigned short* T = (z == 0) ? T0 : (z == 1) ? T1 : (z == 2) ? T2 : T3;
    int t = blockIdx.x * blockDim.x + threadIdx.x;   // 512*512
    int k = t & 511;
    T[t] = f2bf(W[k * HID_ + (t >> 9)]);
}

// ---------------- QKV projection GEMM (bf16 MFMA, fp32 accum) ----------------
//   z=0: Q[b,h,s,d] (pre-scaled by 0.125*log2e)  z=1: K[b,h,s,d]  z=2: Vt[b,h,d,s]
__global__ __launch_bounds__(256) void k_gemm_qkv(
    const unsigned short* __restrict__ Abf,
    const unsigned short* __restrict__ Wqt, const unsigned short* __restrict__ Wkt,
    const unsigned short* __restrict__ Wvt,
    const float* __restrict__ bq, const float* __restrict__ bk, const float* __restrict__ bv,
    unsigned short* __restrict__ Q, unsigned short* __restrict__ K, unsigned short* __restrict__ Vt)
{
    const int z = blockIdx.z;
    const unsigned short* Wt = (z == 0) ? Wqt : ((z == 1) ? Wkt : Wvt);
    const float* bias = (z == 0) ? bq : ((z == 1) ? bk : bv);
    const float osc = (z == 0) ? SCALE_Q : 1.0f;
    const int lane = threadIdx.x & 63, w = threadIdx.x >> 6;
    const int wr = w >> 1, wc = w & 1;
    const int m0 = blockIdx.x * 64 + wr * 32;
    const int n0 = blockIdx.y * 64 + wc * 32;
    const int lr = lane & 15, lg = lane >> 4;

    f4 acc[2][2] = {};
    for (int k0 = 0; k0 < HID_; k0 += 32) {
        const int kk = k0 + lg * 8;
        bf8 a0 = *(const bf8*)&Abf[(size_t)(m0 + lr) * HID_ + kk];
        bf8 a1 = *(const bf8*)&Abf[(size_t)(m0 + 16 + lr) * HID_ + kk];
        bf8 b0 = *(const bf8*)&Wt[(size_t)(n0 + lr) * HID_ + kk];
        bf8 b1 = *(const bf8*)&Wt[(size_t)(n0 + 16 + lr) * HID_ + kk];
        acc[0][0] = MFMA16(a0, b0, acc[0][0]);
        acc[0][1] = MFMA16(a0, b1, acc[0][1]);
        acc[1][0] = MFMA16(a1, b0, acc[1][0]);
        acc[1][1] = MFMA16(a1, b1, acc[1][1]);
    }
    for (int mi = 0; mi < 2; ++mi)
    for (int ni = 0; ni < 2; ++ni)
    for (int r = 0; r < 4; ++r) {
        int row = m0 + mi * 16 + lg * 4 + r;     // token
        int col = n0 + ni * 16 + lr;             // hid
        float v = (acc[mi][ni][r] + bias[col]) * osc;
        unsigned short bf = f2bf(v);
        int b = row >> 11, s = row & 2047;
        int h = col >> 6, d = col & 63;
        if (z == 2) {
            Vt[(((size_t)(b * NH_ + h)) * HD_ + d) * S_ + s] = bf;
        } else {
            unsigned short* dst = (z == 0) ? Q : K;
            dst[(((size_t)(b * NH_ + h)) * S_ + s) * HD_ + d] = bf;
        }
    }
}

// ---------------- output projection GEMM: out fp32 [8192,512] ----------------
__global__ __launch_bounds__(256) void k_gemm_out(
    const unsigned short* __restrict__ Abf,
    const unsigned short* __restrict__ Wot,
    const float* __restrict__ bo,
    float* __restrict__ out)
{
    const int lane = threadIdx.x & 63, w = threadIdx.x >> 6;
    const int wr = w >> 1, wc = w & 1;
    const int m0 = blockIdx.x * 64 + wr * 32;
    const int n0 = blockIdx.y * 64 + wc * 32;
    const int lr = lane & 15, lg = lane >> 4;

    f4 acc[2][2] = {};
    for (int k0 = 0; k0 < HID_; k0 += 32) {
        const int kk = k0 + lg * 8;
        bf8 a0 = *(const bf8*)&Abf[(size_t)(m0 + lr) * HID_ + kk];
        bf8 a1 = *(const bf8*)&Abf[(size_t)(m0 + 16 + lr) * HID_ + kk];
        bf8 b0 = *(const bf8*)&Wot[(size_t)(n0 + lr) * HID_ + kk];
        bf8 b1 = *(const bf8*)&Wot[(size_t)(n0 + 16 + lr) * HID_ + kk];
        acc[0][0] = MFMA16(a0, b0, acc[0][0]);
        acc[0][1] = MFMA16(a0, b1, acc[0][1]);
        acc[1][0] = MFMA16(a1, b0, acc[1][0]);
        acc[1][1] = MFMA16(a1, b1, acc[1][1]);
    }
    for (int mi = 0; mi < 2; ++mi)
    for (int ni = 0; ni < 2; ++ni)
    for (int r = 0; r < 4; ++r) {
        int row = m0 + mi * 16 + lg * 4 + r;
        int col = n0 + ni * 16 + lr;
        out[(size_t)row * HID_ + col] = acc[mi][ni][r] + bo[col];
    }
}

// ---------------- flash attention: LDS-staged shared K/V, double-buffered,
//                  swapped operands, register softmax, 32 q/wave ----------------
// grid 512 (XCD-swizzled); block = 4 waves x 32 q = 128 q rows. K/V tile (64 kv)
// staged once per block into XOR-swizzled LDS, shared by all waves.
__global__ __launch_bounds__(256) void k_flash(
    const unsigned short* __restrict__ Q, const unsigned short* __restrict__ K,
    const unsigned short* __restrict__ Vt,
    const float* __restrict__ rel_table, const float* __restrict__ mask,
    unsigned short* __restrict__ ctx)
{
    __shared__ unsigned short Klds[2][4096];   // [64 kv][64 d], slot^=(row&7) swizzle
    __shared__ unsigned short Vlds[2][4096];   // [64 d][64 kv], same swizzle
    __shared__ unsigned short Ps[4][2][16][72];
    __shared__ float maskc[S_];
    __shared__ float Tb[1025];

    const int t = threadIdx.x;
    const int lane = t & 63, w = t >> 6;
    const int lr = lane & 15, lg = lane >> 4;

    // bijective XCD swizzle: 512 blocks, each XCD owns 4 complete (b,h) pairs
    const int flat = blockIdx.x;
    const int idx = flat >> 3;
    const int bh = (flat & 7) * 4 + (idx >> 4);
    const int qb = idx & 15;
    const int b = bh >> 3, h = bh & 7;
    const int q0 = qb * 128;

    for (int i = t; i < 1025; i += 256) Tb[i] = rel_table[i * NH_ + h] * LOG2E;
    for (int i = t; i < S_; i += 256)
        maskc[i] = (1.0f - mask[b * S_ + i]) * -3.0e38f;

    const unsigned short* Kb = K + (size_t)bh * S_ * HD_;
    const unsigned short* Vb = Vt + (size_t)bh * HD_ * S_;

    // two q column-groups per wave: q = mq0 (g=0), mq0+16 (g=1)
    const int mq0 = q0 + w * 32 + lr;
    bf8 qf00, qf01, qf10, qf11;
    {
        const unsigned short* qg = &Q[((size_t)bh * S_ + mq0) * HD_ + lg * 8];
        qf00 = *(const bf8*)qg;
        qf01 = *(const bf8*)(qg + 32);
        qf10 = *(const bf8*)(qg + 16 * HD_);
        qf11 = *(const bf8*)(qg + 16 * HD_ + 32);
    }

    // staging geometry: wave w covers rows [w*16, w*16+16); lane handles row r0(+8), 16B slot sslot
    const int srow = lane >> 3, sslot = lane & 7;
    const int swz8 = (sslot ^ srow) * 8;          // row&7 == srow for 8-aligned row bases
    const int r0 = w * 16 + srow;
    const int ldso0 = r0 * 64 + swz8;             // ushort offsets into tile
    const int ldso1 = (r0 + 8) * 64 + swz8;

    f4 cacc[8] = {};   // [g*4+dt]; lane holds q=lr(group g), d=dt*16+lg*4+r
    float ms0 = -INFINITY, ls0 = 0.f, ms1 = -INFINITY, ls1 = 0.f;

    // prologue: stage tile 0 into buffer 0
    {
        bf8 a = *(const bf8*)&Kb[(size_t)r0 * HD_ + sslot * 8];
        bf8 c = *(const bf8*)&Kb[(size_t)(r0 + 8) * HD_ + sslot * 8];
        bf8 d = *(const bf8*)&Vb[(size_t)r0 * S_ + sslot * 8];
        bf8 e = *(const bf8*)&Vb[(size_t)(r0 + 8) * S_ + sslot * 8];
        *(bf8*)&Klds[0][ldso0] = a;  *(bf8*)&Klds[0][ldso1] = c;
        *(bf8*)&Vlds[0][ldso0] = d;  *(bf8*)&Vlds[0][ldso1] = e;
    }
    __syncthreads();

    const int xr = lr & 7;
    for (int ti = 0; ti < 32; ++ti) {
        const int cur = ti & 1;
        const int kv0 = ti * 64;

        // issue next tile's global loads early (consumed by ds_write at tile end)
        bf8 s0, s1, s2, s3;
        if (ti < 31) {
            const int nx = kv0 + 64;
            s0 = *(const bf8*)&Kb[(size_t)(nx + r0) * HD_ + sslot * 8];
            s1 = *(const bf8*)&Kb[(size_t)(nx + r0 + 8) * HD_ + sslot * 8];
            s2 = *(const bf8*)&Vb[(size_t)r0 * S_ + nx + sslot * 8];
            s3 = *(const bf8*)&Vb[(size_t)(r0 + 8) * S_ + nx + sslot * 8];
        }

        // ---- QK^T (swapped): S^T[key][q], K A-frags shared by both q-groups ----
        f4 sa[4], sb[4];
        #pragma unroll
        for (int nt = 0; nt < 4; ++nt) {
            const int row = (nt * 16 + lr) * 64;
            bf8 kf0 = *(const bf8*)&Klds[cur][row + ((0 + lg) ^ xr) * 8];
            bf8 kf1 = *(const bf8*)&Klds[cur][row + ((4 + lg) ^ xr) * 8];
            f4 u = {};
            u = MFMA16(kf0, qf00, u); u = MFMA16(kf1, qf01, u);
            sa[nt] = u;
            f4 v = {};
            v = MFMA16(kf0, qf10, v); v = MFMA16(kf1, qf11, v);
            sb[nt] = v;
        }

        // mask values (keys only; shared by both groups), aligned float4 broadcast
        float4 mk[4];
        #pragma unroll
        for (int nt = 0; nt < 4; ++nt)
            mk[nt] = *(const float4*)&maskc[kv0 + nt * 16 + lg * 4];

        // ---- softmax group 0 ----
        {
            float mnew = ms0;
            #pragma unroll
            for (int nt = 0; nt < 4; ++nt)
                #pragma unroll
                for (int r = 0; r < 4; ++r) {
                    int rel = kv0 + nt * 16 + lg * 4 + r - mq0;
                    rel = rel < -MAXREL ? -MAXREL : (rel > MAXREL ? MAXREL : rel);
                    float mkv = (r == 0) ? mk[nt].x : (r == 1) ? mk[nt].y : (r == 2) ? mk[nt].z : mk[nt].w;
                    float sv = sa[nt][r] + Tb[rel + MAXREL] + mkv;
                    sa[nt][r] = sv;
                    mnew = fmaxf(mnew, sv);
                }
            mnew = fmaxf(mnew, __shfl_xor(mnew, 16));
            mnew = fmaxf(mnew, __shfl_xor(mnew, 32));
            const float fac = ex2(ms0 - mnew);
            float psum = 0.f;
            unsigned int pk[8];
            #pragma unroll
            for (int nt = 0; nt < 4; ++nt) {
                float p0 = ex2(sa[nt][0] - mnew);
                float p1 = ex2(sa[nt][1] - mnew);
                float p2 = ex2(sa[nt][2] - mnew);
                float p3 = ex2(sa[nt][3] - mnew);
                psum += (p0 + p1) + (p2 + p3);
                asm("v_cvt_pk_bf16_f32 %0, %1, %2" : "=v"(pk[nt * 2])     : "v"(p0), "v"(p1));
                asm("v_cvt_pk_bf16_f32 %0, %1, %2" : "=v"(pk[nt * 2 + 1]) : "v"(p2), "v"(p3));
            }
            psum += __shfl_xor(psum, 16);
            psum += __shfl_xor(psum, 32);
            ls0 = ls0 * fac + psum;
            ms0 = mnew;
            #pragma unroll
            for (int dt = 0; dt < 4; ++dt)
                #pragma unroll
                for (int r = 0; r < 4; ++r) cacc[dt][r] *= fac;
            #pragma unroll
            for (int nt = 0; nt < 4; ++nt) {
                uint2 pv; pv.x = pk[nt * 2]; pv.y = pk[nt * 2 + 1];
                *(uint2*)&Ps[w][0][lr][nt * 16 + lg * 4] = pv;
            }
        }
        // ---- softmax group 1 ----
        {
            float mnew = ms1;
            #pragma unroll
            for (int nt = 0; nt < 4; ++nt)
                #pragma unroll
                for (int r = 0; r < 4; ++r) {
                    int rel = kv0 + nt * 16 + lg * 4 + r - (mq0 + 16);
                    rel = rel < -MAXREL ? -MAXREL : (rel > MAXREL ? MAXREL : rel);
                    float mkv = (r == 0) ? mk[nt].x : (r == 1) ? mk[nt].y : (r == 2) ? mk[nt].z : mk[nt].w;
                    float sv = sb[nt][r] + Tb[rel + MAXREL] + mkv;
                    sb[nt][r] = sv;
                    mnew = fmaxf(mnew, sv);
                }
            mnew = fmaxf(mnew, __shfl_xor(mnew, 16));
            mnew = fmaxf(mnew, __shfl_xor(mnew, 32));
            const float fac = ex2(ms1 - mnew);
            float psum = 0.f;
            unsigned int pk[8];
            #pragma unroll
            for (int nt = 0; nt < 4; ++nt) {
                float p0 = ex2(sb[nt][0] - mnew);
                float p1 = ex2(sb[nt][1] - mnew);
                float p2 = ex2(sb[nt][2] - mnew);
                float p3 = ex2(sb[nt][3] - mnew);
                psum += (p0 + p1) + (p2 + p3);
                asm("v_cvt_pk_bf16_f32 %0, %1, %2" : "=v"(pk[nt * 2])     : "v"(p0), "v"(p1));
                asm("v_cvt_pk_bf16_f32 %0, %1, %2" : "=v"(pk[nt * 2 + 1]) : "v"(p2), "v"(p3));
            }
            psum += __shfl_xor(psum, 16);
            psum += __shfl_xor(psum, 32);
            ls1 = ls1 * fac + psum;
            ms1 = mnew;
            #pragma unroll
            for (int dt = 0; dt < 4; ++dt)
                #pragma unroll
                for (int r = 0; r < 4; ++r) cacc[4 + dt][r] *= fac;
            #pragma unroll
            for (int nt = 0; nt < 4; ++nt) {
                uint2 pv; pv.x = pk[nt * 2]; pv.y = pk[nt * 2 + 1];
                *(uint2*)&Ps[w][1][lr][nt * 16 + lg * 4] = pv;
            }
        }

        // same-wave ds_write -> ds_read fence (rule #18)
        asm volatile("s_waitcnt lgkmcnt(0)" ::: "memory");
        __builtin_amdgcn_sched_barrier(0);

        // ---- PV (swapped): ctx^T += mfma(V^T, P), V A-frags shared by groups ----
        #pragma unroll
        for (int kc = 0; kc < 2; ++kc) {
            bf8 p0 = *(const bf8*)&Ps[w][0][lr][kc * 32 + lg * 8];
            bf8 p1 = *(const bf8*)&Ps[w][1][lr][kc * 32 + lg * 8];
            #pragma unroll
            for (int dt = 0; dt < 4; ++dt) {
                const int row = (dt * 16 + lr) * 64;
                bf8 vf = *(const bf8*)&Vlds[cur][row + ((kc * 4 + lg) ^ xr) * 8];
                cacc[dt]     = MFMA16(vf, p0, cacc[dt]);
                cacc[4 + dt] = MFMA16(vf, p1, cacc[4 + dt]);
            }
        }

        // ---- stage next tile into buf^1 (compiler inserts vmcnt before writes) ----
        if (ti < 31) {
            const int nxt = cur ^ 1;
            *(bf8*)&Klds[nxt][ldso0] = s0;  *(bf8*)&Klds[nxt][ldso1] = s1;
            *(bf8*)&Vlds[nxt][ldso0] = s2;  *(bf8*)&Vlds[nxt][ldso1] = s3;
        }
        __syncthreads();
    }

    // ---- epilogue: divide by l, write ctx (8B stores, d-contiguous) ----
    const float inv0 = 1.0f / ls0;
    const float inv1 = 1.0f / ls1;
    unsigned short* cg0 = &ctx[(size_t)(b * S_ + mq0) * HID_ + h * HD_];
    unsigned short* cg1 = cg0 + (size_t)16 * HID_;
    #pragma unroll
    for (int dt = 0; dt < 4; ++dt) {
        ushort4 o;
        o.x = f2bf(cacc[dt][0] * inv0);
        o.y = f2bf(cacc[dt][1] * inv0);
        o.z = f2bf(cacc[dt][2] * inv0);
        o.w = f2bf(cacc[dt][3] * inv0);
        *(ushort4*)&cg0[dt * 16 + lg * 4] = o;
        ushort4 o1;
        o1.x = f2bf(cacc[4 + dt][0] * inv1);
        o1.y = f2bf(cacc[4 + dt][1] * inv1);
        o1.z = f2bf(cacc[4 + dt][2] * inv1);
        o1.w = f2bf(cacc[4 + dt][3] * inv1);
        *(ushort4*)&cg1[dt * 16 + lg * 4] = o1;
    }
}

// ---------------- launcher ----------------
extern "C" void kernel_launch(void* const* d_in, const int* in_sizes, int n_in,
                              void* d_out, int out_size, void* d_ws, size_t ws_size,
                              hipStream_t stream) {
    const float* hs  = (const float*)d_in[0];
    const float* msk = (const float*)d_in[1];
    const float* Wq  = (const float*)d_in[2];
    const float* bq  = (const float*)d_in[3];
    const float* Wk  = (const float*)d_in[4];
    const float* bk  = (const float*)d_in[5];
    const float* Wv  = (const float*)d_in[6];
    const float* bv  = (const float*)d_in[7];
    const float* Wo  = (const float*)d_in[8];
    const float* bo  = (const float*)d_in[9];
    const float* rel = (const float*)d_in[10];
    float* out = (float*)d_out;

    char* ws = (char*)d_ws;
    unsigned short* hsb = (unsigned short*)ws; ws += (size_t)M_ * HID_ * 2;
    unsigned short* Wqt = (unsigned short*)ws; ws += (size_t)HID_ * HID_ * 2;
    unsigned short* Wkt = (unsigned short*)ws; ws += (size_t)HID_ * HID_ * 2;
    unsigned short* Wvt = (unsigned short*)ws; ws += (size_t)HID_ * HID_ * 2;
    unsigned short* Wot = (unsigned short*)ws; ws += (size_t)HID_ * HID_ * 2;
    unsigned short* Qb  = (unsigned short*)ws; ws += (size_t)M_ * HID_ * 2;
    unsigned short* Kb  = (unsigned short*)ws; ws += (size_t)M_ * HID_ * 2;
    unsigned short* Vtb = (unsigned short*)ws; ws += (size_t)M_ * HID_ * 2;
    unsigned short* ctxb= (unsigned short*)ws; ws += (size_t)M_ * HID_ * 2;

    k_cast_hs<<<(M_ * HID_ / 4 + 255) / 256, 256, 0, stream>>>(hs, hsb, M_ * HID_ / 4);
    k_transpose_w4<<<dim3(1024, 4), 256, 0, stream>>>(Wq, Wk, Wv, Wo, Wqt, Wkt, Wvt, Wot);
    k_gemm_qkv<<<dim3(M_ / 64, HID_ / 64, 3), 256, 0, stream>>>(
        hsb, Wqt, Wkt, Wvt, bq, bk, bv, Qb, Kb, Vtb);
    k_flash<<<512, 256, 0, stream>>>(Qb, Kb, Vtb, rel, msk, ctxb);
    k_gemm_out<<<dim3(M_ / 64, HID_ / 64), 256, 0, stream>>>(ctxb, Wot, bo, out);
}

// Round 5
// 124.985 us; speedup vs baseline: 3.1322x; 1.7910x over previous
//
#include <hip/hip_runtime.h>
#include <hip/hip_bf16.h>

#define B_    4
#define S_    2048
#define HID_  512
#define NH_   8
#define HD_   64
#define MAXREL 512
#define M_    (B_ * S_)   // 8192 tokens

#define LOG2E 1.44269504f
#define SCALE_Q (0.125f * LOG2E)   // folded into Q at projection time

typedef __attribute__((ext_vector_type(8))) short bf8;            // 8 bf16 (MFMA A/B frag)
typedef __attribute__((ext_vector_type(4))) float f4;             // MFMA C/D frag

static __device__ __forceinline__ unsigned short f2bf(float f) {
    union { float f; unsigned int u; } v; v.f = f;
    unsigned int u = v.u;
    unsigned int r = (u + 0x7FFFu + ((u >> 16) & 1u)) >> 16;   // round-nearest-even
    return (unsigned short)r;
}

static __device__ __forceinline__ float ex2(float x) {   // raw v_exp_f32 (base-2)
    float r; asm("v_exp_f32 %0, %1" : "=v"(r) : "v"(x)); return r;
}

#define MFMA16(a, b, c) __builtin_amdgcn_mfma_f32_16x16x32_bf16((a), (b), (c), 0, 0, 0)

// ---------------- cast hidden_states fp32 -> bf16 ----------------
__global__ void k_cast_hs(const float* __restrict__ src, unsigned short* __restrict__ dst, int n4) {
    int i = blockIdx.x * blockDim.x + threadIdx.x;
    if (i >= n4) return;
    float4 v = ((const float4*)src)[i];
    ushort4 o;
    o.x = f2bf(v.x); o.y = f2bf(v.y); o.z = f2bf(v.z); o.w = f2bf(v.w);
    ((ushort4*)dst)[i] = o;
}

// ---------------- transpose + cast 4 weights (LDS 32x32 tiles) ----------------
__global__ void k_transpose_w4(const float* __restrict__ W0, const float* __restrict__ W1,
                               const float* __restrict__ W2, const float* __restrict__ W3,
                               unsigned short* __restrict__ T0, unsigned short* __restrict__ T1,
                               unsigned short* __restrict__ T2, unsigned short* __restrict__ T3) {
    __shared__ float tile[32][33];
    const int z = blockIdx.z;
    const float* W = (z == 0) ? W0 : (z == 1) ? W1 : (z == 2) ? W2 : W3;
    unsigned short* T = (z == 0) ? T0 : (z == 1) ? T1 : (z == 2) ? T2 : T3;
    const int tx = threadIdx.x & 31, ty = threadIdx.x >> 5;   // 256 thr
    const int n0 = blockIdx.x * 32, k0 = blockIdx.y * 32;
    #pragma unroll
    for (int i = 0; i < 4; ++i)
        tile[ty + i * 8][tx] = W[(size_t)(k0 + ty + i * 8) * HID_ + n0 + tx];
    __syncthreads();
    #pragma unroll
    for (int i = 0; i < 4; ++i)
        T[(size_t)(n0 + ty + i * 8) * HID_ + k0 + tx] = f2bf(tile[tx][ty + i * 8]);
}

// ---------------- fused QKV GEMM: 128x128 tile, dbuf LDS, 2-phase ----------------
// A[8192,512] bf16 x Wt(z)[512,512] -> z=0: Q (pre-scaled), z=1: K, z=2: Vt[b,h,d,s]
__global__ __launch_bounds__(256, 3) void k_gemm_qkv(
    const unsigned short* __restrict__ Abf,
    const unsigned short* __restrict__ Wqt, const unsigned short* __restrict__ Wkt,
    const unsigned short* __restrict__ Wvt,
    const float* __restrict__ bq, const float* __restrict__ bk, const float* __restrict__ bv,
    unsigned short* __restrict__ Q, unsigned short* __restrict__ K, unsigned short* __restrict__ Vt)
{
    __shared__ unsigned short Al[2][128 * 32];
    __shared__ unsigned short Bl[2][128 * 32];

    const int t = threadIdx.x;
    const int lane = t & 63, w = t >> 6;
    const int lr = lane & 15, lg = lane >> 4;
    const int wr = w >> 1, wc = w & 1;

    const int m0 = blockIdx.x * 128;
    const int ng = blockIdx.y * 128;
    const int z = ng >> 9;
    const int n0 = ng & 511;
    const unsigned short* Wt = (z == 0) ? Wqt : ((z == 1) ? Wkt : Wvt);
    const float* bias = (z == 0) ? bq : ((z == 1) ? bk : bv);
    const float osc = (z == 0) ? SCALE_Q : 1.0f;

    // staging: thread t, chunk i in {0,1}: row = t/4 + i*64, kk = (t&3)*8
    const int srow = t >> 2, skk = (t & 3) * 8;
    const int sslot = (t & 3) ^ ((srow >> 1) & 3);          // XOR swizzle (2-way free)
    const int so0 = srow * 32 + sslot * 8;
    const int so1 = (srow + 64) * 32 + sslot * 8;
    const unsigned short* Ag = &Abf[(size_t)(m0 + srow) * HID_ + skk];
    const unsigned short* Bg = &Wt[(size_t)(n0 + srow) * HID_ + skk];

    // fragment read offsets
    const int fx = (lr >> 1) & 3;
    int aoff[4], boff[4];
    #pragma unroll
    for (int i = 0; i < 4; ++i) {
        aoff[i] = (wr * 64 + i * 16 + lr) * 32 + ((lg ^ fx) * 8);
        boff[i] = (wc * 64 + i * 16 + lr) * 32 + ((lg ^ fx) * 8);
    }

    // prologue: stage k0=0 into buf 0
    {
        bf8 a0 = *(const bf8*)Ag;
        bf8 a1 = *(const bf8*)(Ag + (size_t)64 * HID_);
        bf8 b0 = *(const bf8*)Bg;
        bf8 b1 = *(const bf8*)(Bg + (size_t)64 * HID_);
        *(bf8*)&Al[0][so0] = a0;  *(bf8*)&Al[0][so1] = a1;
        *(bf8*)&Bl[0][so0] = b0;  *(bf8*)&Bl[0][so1] = b1;
    }
    __syncthreads();

    f4 acc[4][4] = {};
    for (int kt = 0; kt < 16; ++kt) {
        const int cur = kt & 1;
        bf8 ra0, ra1, rb0, rb1;
        if (kt < 15) {
            const int ko = (kt + 1) * 32;
            ra0 = *(const bf8*)(Ag + ko);
            ra1 = *(const bf8*)(Ag + (size_t)64 * HID_ + ko);
            rb0 = *(const bf8*)(Bg + ko);
            rb1 = *(const bf8*)(Bg + (size_t)64 * HID_ + ko);
        }
        bf8 af[4], bf_[4];
        #pragma unroll
        for (int i = 0; i < 4; ++i) {
            af[i]  = *(const bf8*)&Al[cur][aoff[i]];
            bf_[i] = *(const bf8*)&Bl[cur][boff[i]];
        }
        #pragma unroll
        for (int mi = 0; mi < 4; ++mi)
            #pragma unroll
            for (int ni = 0; ni < 4; ++ni)
                acc[mi][ni] = MFMA16(af[mi], bf_[ni], acc[mi][ni]);
        if (kt < 15) {
            const int nxt = cur ^ 1;
            *(bf8*)&Al[nxt][so0] = ra0;  *(bf8*)&Al[nxt][so1] = ra1;
            *(bf8*)&Bl[nxt][so0] = rb0;  *(bf8*)&Bl[nxt][so1] = rb1;
        }
        __syncthreads();
    }

    // epilogue: scatter per layout
    #pragma unroll
    for (int mi = 0; mi < 4; ++mi)
    #pragma unroll
    for (int ni = 0; ni < 4; ++ni) {
        const int col = n0 + wc * 64 + ni * 16 + lr;    // hid within section
        const int h = col >> 6, d = col & 63;
        const float bs = bias[col];
        const int row0 = m0 + wr * 64 + mi * 16 + lg * 4;
        const int b = row0 >> 11, s0 = row0 & 2047;
        if (z == 2) {
            ushort4 o;
            o.x = f2bf(acc[mi][ni][0] + bs);
            o.y = f2bf(acc[mi][ni][1] + bs);
            o.z = f2bf(acc[mi][ni][2] + bs);
            o.w = f2bf(acc[mi][ni][3] + bs);
            *(ushort4*)&Vt[(((size_t)(b * NH_ + h)) * HD_ + d) * S_ + s0] = o;
        } else {
            unsigned short* dst = (z == 0) ? Q : K;
            #pragma unroll
            for (int r = 0; r < 4; ++r) {
                float v = (acc[mi][ni][r] + bs) * osc;
                dst[(((size_t)(b * NH_ + h)) * S_ + s0 + r) * HD_ + d] = f2bf(v);
            }
        }
    }
}

// ---------------- output projection GEMM: 128x128 tile, 512 threads ----------------
__global__ __launch_bounds__(512) void k_gemm_out(
    const unsigned short* __restrict__ Abf,
    const unsigned short* __restrict__ Wot,
    const float* __restrict__ bo,
    float* __restrict__ out)
{
    __shared__ unsigned short Al[2][128 * 32];
    __shared__ unsigned short Bl[2][128 * 32];

    const int t = threadIdx.x;
    const int lane = t & 63, w = t >> 6;          // 8 waves, 2x4
    const int lr = lane & 15, lg = lane >> 4;
    const int wr = w >> 2, wc = w & 3;

    const int m0 = blockIdx.x * 128;
    const int n0 = blockIdx.y * 128;

    const int srow = t >> 2, skk = (t & 3) * 8;   // one chunk per array per thread
    const int sslot = (t & 3) ^ ((srow >> 1) & 3);
    const int so = srow * 32 + sslot * 8;
    const unsigned short* Ag = &Abf[(size_t)(m0 + srow) * HID_ + skk];
    const unsigned short* Bg = &Wot[(size_t)(n0 + srow) * HID_ + skk];

    const int fx = (lr >> 1) & 3;
    int aoff[4], boff[2];
    #pragma unroll
    for (int i = 0; i < 4; ++i)
        aoff[i] = (wr * 64 + i * 16 + lr) * 32 + ((lg ^ fx) * 8);
    #pragma unroll
    for (int i = 0; i < 2; ++i)
        boff[i] = (wc * 32 + i * 16 + lr) * 32 + ((lg ^ fx) * 8);

    {
        bf8 a0 = *(const bf8*)Ag;
        bf8 b0 = *(const bf8*)Bg;
        *(bf8*)&Al[0][so] = a0;
        *(bf8*)&Bl[0][so] = b0;
    }
    __syncthreads();

    f4 acc[4][2] = {};
    for (int kt = 0; kt < 16; ++kt) {
        const int cur = kt & 1;
        bf8 ra, rb;
        if (kt < 15) {
            const int ko = (kt + 1) * 32;
            ra = *(const bf8*)(Ag + ko);
            rb = *(const bf8*)(Bg + ko);
        }
        bf8 af[4], bf_[2];
        #pragma unroll
        for (int i = 0; i < 4; ++i) af[i] = *(const bf8*)&Al[cur][aoff[i]];
        #pragma unroll
        for (int i = 0; i < 2; ++i) bf_[i] = *(const bf8*)&Bl[cur][boff[i]];
        #pragma unroll
        for (int mi = 0; mi < 4; ++mi)
            #pragma unroll
            for (int ni = 0; ni < 2; ++ni)
                acc[mi][ni] = MFMA16(af[mi], bf_[ni], acc[mi][ni]);
        if (kt < 15) {
            const int nxt = cur ^ 1;
            *(bf8*)&Al[nxt][so] = ra;
            *(bf8*)&Bl[nxt][so] = rb;
        }
        __syncthreads();
    }

    #pragma unroll
    for (int mi = 0; mi < 4; ++mi)
    #pragma unroll
    for (int ni = 0; ni < 2; ++ni) {
        const int col = n0 + wc * 32 + ni * 16 + lr;
        const float bs = bo[col];
        const int row0 = m0 + wr * 64 + mi * 16 + lg * 4;
        #pragma unroll
        for (int r = 0; r < 4; ++r)
            out[(size_t)(row0 + r) * HID_ + col] = acc[mi][ni][r] + bs;
    }
}

// ---------------- flash attention: 8 waves x 16 q, LDS-staged shared K/V ----------------
// 512 blocks (XCD-swizzled) x 512 threads -> 4 waves/SIMD. Swapped-operand MFMA,
// register softmax (2 shfl), defer-max, double-buffered K/V, no inter-wave sync
// except the staging barrier.
__global__ __launch_bounds__(512, 4) void k_flash(
    const unsigned short* __restrict__ Q, const unsigned short* __restrict__ K,
    const unsigned short* __restrict__ Vt,
    const float* __restrict__ rel_table, const float* __restrict__ mask,
    unsigned short* __restrict__ ctx)
{
    __shared__ unsigned short Klds[2][4096];   // [64 kv][64 d], slot^=(row&7)
    __shared__ unsigned short Vlds[2][4096];   // [64 d][64 kv], same swizzle
    __shared__ unsigned short Ps[8][16][72];   // wave-private P tile (72-pad)
    __shared__ float maskc[S_];
    __shared__ float Tb[1028];                 // 1025 used

    const int t = threadIdx.x;
    const int lane = t & 63, w = t >> 6;       // 8 waves
    const int lr = lane & 15, lg = lane >> 4;

    // bijective XCD swizzle: each XCD owns 4 complete (b,h) pairs
    const int flat = blockIdx.x;               // 0..511
    const int idx = flat >> 3;
    const int bh = (flat & 7) * 4 + (idx >> 4);
    const int qb = idx & 15;
    const int b = bh >> 3, h = bh & 7;
    const int q0 = qb * 128;

    for (int i = t; i < 1025; i += 512) Tb[i] = rel_table[i * NH_ + h] * LOG2E;
    for (int i = t; i < S_; i += 512)
        maskc[i] = (1.0f - mask[b * S_ + i]) * -3.0e38f;

    const unsigned short* Kb = K + (size_t)bh * S_ * HD_;
    const unsigned short* Vb = Vt + (size_t)bh * HD_ * S_;

    const int myq = q0 + w * 16 + lr;
    bf8 qf0, qf1;
    {
        const unsigned short* qg = &Q[((size_t)bh * S_ + myq) * HD_ + lg * 8];
        qf0 = *(const bf8*)qg;
        qf1 = *(const bf8*)(qg + 32);
    }

    // staging: thread t handles row = t>>3 (0..63), 16B slot = t&7
    const int srow = t >> 3, sslot = t & 7;
    const int ldso = srow * 64 + ((sslot ^ (srow & 7)) * 8);

    f4 cacc[4] = {};
    float m_s = -INFINITY, l_s = 0.f;

    // prologue: stage tile 0 into buffer 0
    {
        bf8 a = *(const bf8*)&Kb[(size_t)srow * HD_ + sslot * 8];
        bf8 d = *(const bf8*)&Vb[(size_t)srow * S_ + sslot * 8];
        *(bf8*)&Klds[0][ldso] = a;
        *(bf8*)&Vlds[0][ldso] = d;
    }
    __syncthreads();

    const int xr = lr & 7;
    for (int ti = 0; ti < 32; ++ti) {
        const int cur = ti & 1;
        const int kv0 = ti * 64;

        // early-issue next tile's global loads (T14)
        bf8 sK, sV;
        if (ti < 31) {
            const int nx = kv0 + 64;
            sK = *(const bf8*)&Kb[(size_t)(nx + srow) * HD_ + sslot * 8];
            sV = *(const bf8*)&Vb[(size_t)srow * S_ + nx + sslot * 8];
        }

        // ---- QK^T (swapped): S^T[key][q] ----
        f4 sa[4];
        #pragma unroll
        for (int nt = 0; nt < 4; ++nt) {
            const int row = (nt * 16 + lr) * 64;
            bf8 kf0 = *(const bf8*)&Klds[cur][row + ((0 + lg) ^ xr) * 8];
            bf8 kf1 = *(const bf8*)&Klds[cur][row + ((4 + lg) ^ xr) * 8];
            f4 u = {};
            u = MFMA16(kf0, qf0, u);
            u = MFMA16(kf1, qf1, u);
            sa[nt] = u;
        }

        // ---- bias + mask + tile max ----
        float4 mk[4];
        #pragma unroll
        for (int nt = 0; nt < 4; ++nt)
            mk[nt] = *(const float4*)&maskc[kv0 + nt * 16 + lg * 4];

        float tmax = -INFINITY;
        #pragma unroll
        for (int nt = 0; nt < 4; ++nt) {
            const int kb0 = kv0 + nt * 16 + lg * 4 - myq + MAXREL;
            #pragma unroll
            for (int r = 0; r < 4; ++r) {
                int ic = kb0 + r;
                ic = ic < 0 ? 0 : (ic > 2 * MAXREL ? 2 * MAXREL : ic);
                float mkv = (r == 0) ? mk[nt].x : (r == 1) ? mk[nt].y : (r == 2) ? mk[nt].z : mk[nt].w;
                float sv = sa[nt][r] + Tb[ic] + mkv;
                sa[nt][r] = sv;
                tmax = fmaxf(tmax, sv);
            }
        }
        tmax = fmaxf(tmax, __shfl_xor(tmax, 16));
        tmax = fmaxf(tmax, __shfl_xor(tmax, 32));

        // ---- defer-max (T13, THR=8 in base-2 domain) ----
        if (!__all(tmax <= m_s + 8.0f)) {
            const float mnew = fmaxf(m_s, tmax);
            const float fac = ex2(m_s - mnew);
            l_s *= fac;
            #pragma unroll
            for (int dt = 0; dt < 4; ++dt)
                #pragma unroll
                for (int r = 0; r < 4; ++r) cacc[dt][r] *= fac;
            m_s = mnew;
        }

        float psum = 0.f;
        unsigned int pk[8];
        #pragma unroll
        for (int nt = 0; nt < 4; ++nt) {
            float p0 = ex2(sa[nt][0] - m_s);
            float p1 = ex2(sa[nt][1] - m_s);
            float p2 = ex2(sa[nt][2] - m_s);
            float p3 = ex2(sa[nt][3] - m_s);
            psum += (p0 + p1) + (p2 + p3);
            asm("v_cvt_pk_bf16_f32 %0, %1, %2" : "=v"(pk[nt * 2])     : "v"(p0), "v"(p1));
            asm("v_cvt_pk_bf16_f32 %0, %1, %2" : "=v"(pk[nt * 2 + 1]) : "v"(p2), "v"(p3));
        }
        psum += __shfl_xor(psum, 16);
        psum += __shfl_xor(psum, 32);
        l_s += psum;

        // ---- wave-local P transpose through LDS ----
        #pragma unroll
        for (int nt = 0; nt < 4; ++nt) {
            uint2 pv; pv.x = pk[nt * 2]; pv.y = pk[nt * 2 + 1];
            *(uint2*)&Ps[w][lr][nt * 16 + lg * 4] = pv;
        }
        asm volatile("s_waitcnt lgkmcnt(0)" ::: "memory");
        __builtin_amdgcn_sched_barrier(0);

        // ---- PV (swapped): ctx^T += mfma(V^T, P) ----
        #pragma unroll
        for (int kc = 0; kc < 2; ++kc) {
            bf8 pb = *(const bf8*)&Ps[w][lr][kc * 32 + lg * 8];
            #pragma unroll
            for (int dt = 0; dt < 4; ++dt) {
                const int row = (dt * 16 + lr) * 64;
                bf8 vf = *(const bf8*)&Vlds[cur][row + ((kc * 4 + lg) ^ xr) * 8];
                cacc[dt] = MFMA16(vf, pb, cacc[dt]);
            }
        }

        // ---- write next tile into buf^1 ----
        if (ti < 31) {
            *(bf8*)&Klds[cur ^ 1][ldso] = sK;
            *(bf8*)&Vlds[cur ^ 1][ldso] = sV;
        }
        __syncthreads();
    }

    // ---- epilogue ----
    const float inv = 1.0f / l_s;
    unsigned short* cg = &ctx[(size_t)(b * S_ + myq) * HID_ + h * HD_];
    #pragma unroll
    for (int dt = 0; dt < 4; ++dt) {
        ushort4 o;
        o.x = f2bf(cacc[dt][0] * inv);
        o.y = f2bf(cacc[dt][1] * inv);
        o.z = f2bf(cacc[dt][2] * inv);
        o.w = f2bf(cacc[dt][3] * inv);
        *(ushort4*)&cg[dt * 16 + lg * 4] = o;
    }
}

// ---------------- launcher ----------------
extern "C" void kernel_launch(void* const* d_in, const int* in_sizes, int n_in,
                              void* d_out, int out_size, void* d_ws, size_t ws_size,
                              hipStream_t stream) {
    const float* hs  = (const float*)d_in[0];
    const float* msk = (const float*)d_in[1];
    const float* Wq  = (const float*)d_in[2];
    const float* bq  = (const float*)d_in[3];
    const float* Wk  = (const float*)d_in[4];
    const float* bk  = (const float*)d_in[5];
    const float* Wv  = (const float*)d_in[6];
    const float* bv  = (const float*)d_in[7];
    const float* Wo  = (const float*)d_in[8];
    const float* bo  = (const float*)d_in[9];
    const float* rel = (const float*)d_in[10];
    float* out = (float*)d_out;

    char* ws = (char*)d_ws;
    unsigned short* hsb = (unsigned short*)ws; ws += (size_t)M_ * HID_ * 2;
    unsigned short* Wqt = (unsigned short*)ws; ws += (size_t)HID_ * HID_ * 2;
    unsigned short* Wkt = (unsigned short*)ws; ws += (size_t)HID_ * HID_ * 2;
    unsigned short* Wvt = (unsigned short*)ws; ws += (size_t)HID_ * HID_ * 2;
    unsigned short* Wot = (unsigned short*)ws; ws += (size_t)HID_ * HID_ * 2;
    unsigned short* Qb  = (unsigned short*)ws; ws += (size_t)M_ * HID_ * 2;
    unsigned short* Kb  = (unsigned short*)ws; ws += (size_t)M_ * HID_ * 2;
    unsigned short* Vtb = (unsigned short*)ws; ws += (size_t)M_ * HID_ * 2;
    unsigned short* ctxb= (unsigned short*)ws; ws += (size_t)M_ * HID_ * 2;

    k_cast_hs<<<(M_ * HID_ / 4 + 255) / 256, 256, 0, stream>>>(hs, hsb, M_ * HID_ / 4);
    k_transpose_w4<<<dim3(16, 16, 4), 256, 0, stream>>>(Wq, Wk, Wv, Wo, Wqt, Wkt, Wvt, Wot);
    k_gemm_qkv<<<dim3(64, 12), 256, 0, stream>>>(
        hsb, Wqt, Wkt, Wvt, bq, bk, bv, Qb, Kb, Vtb);
    k_flash<<<512, 512, 0, stream>>>(Qb, Kb, Vtb, rel, msk, ctxb);
    k_gemm_out<<<dim3(64, 4), 512, 0, stream>>>(ctxb, Wot, bo, out);
}

// Round 6
// 117.054 us; speedup vs baseline: 3.3444x; 1.0678x over previous
//
#include <hip/hip_runtime.h>
#include <hip/hip_bf16.h>

#define B_    4
#define S_    2048
#define HID_  512
#define NH_   8
#define HD_   64
#define MAXREL 512
#define M_    (B_ * S_)   // 8192 tokens

#define LOG2E 1.44269504f
#define SCALE_Q (0.125f * LOG2E)   // folded into Q at projection time

typedef __attribute__((ext_vector_type(8))) short bf8;            // 8 bf16 (MFMA A/B frag)
typedef __attribute__((ext_vector_type(4))) float f4;             // MFMA C/D frag

static __device__ __forceinline__ unsigned short f2bf(float f) {
    union { float f; unsigned int u; } v; v.f = f;
    unsigned int u = v.u;
    unsigned int r = (u + 0x7FFFu + ((u >> 16) & 1u)) >> 16;   // round-nearest-even
    return (unsigned short)r;
}

static __device__ __forceinline__ float ex2(float x) {   // raw v_exp_f32 (base-2)
    float r; asm("v_exp_f32 %0, %1" : "=v"(r) : "v"(x)); return r;
}

// async global->LDS, 16B per lane; dest = wave-uniform base + lane*16 (linear)
static __device__ __forceinline__ void gload16(const void* g, void* l) {
    __builtin_amdgcn_global_load_lds(
        (const __attribute__((address_space(1))) unsigned int*)g,
        (__attribute__((address_space(3))) unsigned int*)l, 16, 0, 0);
}

#define MFMA16(a, b, c) __builtin_amdgcn_mfma_f32_16x16x32_bf16((a), (b), (c), 0, 0, 0)

// ---------------- cast hidden_states fp32 -> bf16 ----------------
__global__ void k_cast_hs(const float* __restrict__ src, unsigned short* __restrict__ dst, int n4) {
    int i = blockIdx.x * blockDim.x + threadIdx.x;
    if (i >= n4) return;
    float4 v = ((const float4*)src)[i];
    ushort4 o;
    o.x = f2bf(v.x); o.y = f2bf(v.y); o.z = f2bf(v.z); o.w = f2bf(v.w);
    ((ushort4*)dst)[i] = o;
}

// ---------------- mask -> additive form (0 attend / -3e38 masked) ----------------
__global__ void k_prep_mask(const float* __restrict__ mask, float* __restrict__ maskadd) {
    int i = blockIdx.x * blockDim.x + threadIdx.x;
    if (i < M_) maskadd[i] = (1.0f - mask[i]) * -3.0e38f;
}

// ---------------- transpose + cast 4 weights (LDS 32x32 tiles) ----------------
__global__ void k_transpose_w4(const float* __restrict__ W0, const float* __restrict__ W1,
                               const float* __restrict__ W2, const float* __restrict__ W3,
                               unsigned short* __restrict__ T0, unsigned short* __restrict__ T1,
                               unsigned short* __restrict__ T2, unsigned short* __restrict__ T3) {
    __shared__ float tile[32][33];
    const int z = blockIdx.z;
    const float* W = (z == 0) ? W0 : (z == 1) ? W1 : (z == 2) ? W2 : W3;
    unsigned short* T = (z == 0) ? T0 : (z == 1) ? T1 : (z == 2) ? T2 : T3;
    const int tx = threadIdx.x & 31, ty = threadIdx.x >> 5;   // 256 thr
    const int n0 = blockIdx.x * 32, k0 = blockIdx.y * 32;
    #pragma unroll
    for (int i = 0; i < 4; ++i)
        tile[ty + i * 8][tx] = W[(size_t)(k0 + ty + i * 8) * HID_ + n0 + tx];
    __syncthreads();
    #pragma unroll
    for (int i = 0; i < 4; ++i)
        T[(size_t)(n0 + ty + i * 8) * HID_ + k0 + tx] = f2bf(tile[tx][ty + i * 8]);
}

// ---------------- fused QKV GEMM: 128x128 tile, dbuf LDS via global_load_lds ----------------
// A[8192,512] bf16 x Wt(z)[512,512] -> z=0: Q (pre-scaled), z=1: K, z=2: Vt[b,h,d,s]
__global__ __launch_bounds__(256, 3) void k_gemm_qkv(
    const unsigned short* __restrict__ Abf,
    const unsigned short* __restrict__ Wqt, const unsigned short* __restrict__ Wkt,
    const unsigned short* __restrict__ Wvt,
    const float* __restrict__ bq, const float* __restrict__ bk, const float* __restrict__ bv,
    unsigned short* __restrict__ Q, unsigned short* __restrict__ K, unsigned short* __restrict__ Vt)
{
    __shared__ unsigned short Al[2][128 * 32];
    __shared__ unsigned short Bl[2][128 * 32];

    const int t = threadIdx.x;
    const int lane = t & 63, w = t >> 6;
    const int lr = lane & 15, lg = lane >> 4;
    const int wr = w >> 1, wc = w & 1;

    const int m0 = blockIdx.x * 128;
    const int ng = blockIdx.y * 128;
    const int z = ng >> 9;
    const int n0 = ng & 511;
    const unsigned short* Wt = (z == 0) ? Wqt : ((z == 1) ? Wkt : Wvt);
    const float* bias = (z == 0) ? bq : ((z == 1) ? bk : bv);
    const float osc = (z == 0) ? SCALE_Q : 1.0f;

    // staging: thread t -> row t>>2, slot t&3; source col pre-swizzled, LDS dest linear
    const int srow = t >> 2;
    const int sc = (((t & 3) ^ ((srow >> 1) & 3))) * 8;     // swizzled source col (ushorts)
    const unsigned short* Ag0 = &Abf[(size_t)(m0 + srow) * HID_ + sc];
    const unsigned short* Ag1 = &Abf[(size_t)(m0 + 64 + srow) * HID_ + sc];
    const unsigned short* Bg0 = &Wt[(size_t)(n0 + srow) * HID_ + sc];
    const unsigned short* Bg1 = &Wt[(size_t)(n0 + 64 + srow) * HID_ + sc];
    // wave-uniform LDS dest bases (this wave covers rows w*16..w*16+15 of each half)
    char* dA0 = (char*)&Al[0][0] + w * 1024;   // + buf*8192 applied in loop
    char* dB0 = (char*)&Bl[0][0] + w * 1024;

    // fragment read offsets (read-side swizzle matches source pre-swizzle)
    const int fx = (lr >> 1) & 3;
    int aoff[4], boff[4];
    #pragma unroll
    for (int i = 0; i < 4; ++i) {
        aoff[i] = (wr * 64 + i * 16 + lr) * 32 + ((lg ^ fx) * 8);
        boff[i] = (wc * 64 + i * 16 + lr) * 32 + ((lg ^ fx) * 8);
    }

    // prologue: stage k0=0 into buf 0
    gload16(Ag0, dA0);
    gload16(Ag1, dA0 + 4096);
    gload16(Bg0, dB0);
    gload16(Bg1, dB0 + 4096);
    __syncthreads();

    f4 acc[4][4] = {};
    for (int kt = 0; kt < 16; ++kt) {
        const int cur = kt & 1;
        if (kt < 15) {
            const int ko = (kt + 1) * 32;
            const int bo = (cur ^ 1) * 8192;
            gload16(Ag0 + ko, dA0 + bo);
            gload16(Ag1 + ko, dA0 + bo + 4096);
            gload16(Bg0 + ko, dB0 + bo);
            gload16(Bg1 + ko, dB0 + bo + 4096);
        }
        bf8 af[4], bf_[4];
        #pragma unroll
        for (int i = 0; i < 4; ++i) {
            af[i]  = *(const bf8*)&Al[cur][aoff[i]];
            bf_[i] = *(const bf8*)&Bl[cur][boff[i]];
        }
        #pragma unroll
        for (int mi = 0; mi < 4; ++mi)
            #pragma unroll
            for (int ni = 0; ni < 4; ++ni)
                acc[mi][ni] = MFMA16(af[mi], bf_[ni], acc[mi][ni]);
        __syncthreads();
    }

    // epilogue: scatter per layout
    #pragma unroll
    for (int mi = 0; mi < 4; ++mi)
    #pragma unroll
    for (int ni = 0; ni < 4; ++ni) {
        const int col = n0 + wc * 64 + ni * 16 + lr;    // hid within section
        const int h = col >> 6, d = col & 63;
        const float bs = bias[col];
        const int row0 = m0 + wr * 64 + mi * 16 + lg * 4;
        const int b = row0 >> 11, s0 = row0 & 2047;
        if (z == 2) {
            ushort4 o;
            o.x = f2bf(acc[mi][ni][0] + bs);
            o.y = f2bf(acc[mi][ni][1] + bs);
            o.z = f2bf(acc[mi][ni][2] + bs);
            o.w = f2bf(acc[mi][ni][3] + bs);
            *(ushort4*)&Vt[(((size_t)(b * NH_ + h)) * HD_ + d) * S_ + s0] = o;
        } else {
            unsigned short* dst = (z == 0) ? Q : K;
            #pragma unroll
            for (int r = 0; r < 4; ++r) {
                float v = (acc[mi][ni][r] + bs) * osc;
                dst[(((size_t)(b * NH_ + h)) * S_ + s0 + r) * HD_ + d] = f2bf(v);
            }
        }
    }
}

// ---------------- output projection GEMM: 128x128 tile, 512 threads ----------------
__global__ __launch_bounds__(512) void k_gemm_out(
    const unsigned short* __restrict__ Abf,
    const unsigned short* __restrict__ Wot,
    const float* __restrict__ bo,
    float* __restrict__ out)
{
    __shared__ unsigned short Al[2][128 * 32];
    __shared__ unsigned short Bl[2][128 * 32];

    const int t = threadIdx.x;
    const int lane = t & 63, w = t >> 6;          // 8 waves, 2x4
    const int lr = lane & 15, lg = lane >> 4;
    const int wr = w >> 2, wc = w & 3;

    const int m0 = blockIdx.x * 128;
    const int n0 = blockIdx.y * 128;

    const int srow = t >> 2;
    const int sc = (((t & 3) ^ ((srow >> 1) & 3))) * 8;
    const unsigned short* Ag = &Abf[(size_t)(m0 + srow) * HID_ + sc];
    const unsigned short* Bg = &Wot[(size_t)(n0 + srow) * HID_ + sc];
    char* dA = (char*)&Al[0][0] + w * 1024;
    char* dB = (char*)&Bl[0][0] + w * 1024;

    const int fx = (lr >> 1) & 3;
    int aoff[4], boff[2];
    #pragma unroll
    for (int i = 0; i < 4; ++i)
        aoff[i] = (wr * 64 + i * 16 + lr) * 32 + ((lg ^ fx) * 8);
    #pragma unroll
    for (int i = 0; i < 2; ++i)
        boff[i] = (wc * 32 + i * 16 + lr) * 32 + ((lg ^ fx) * 8);

    gload16(Ag, dA);
    gload16(Bg, dB);
    __syncthreads();

    f4 acc[4][2] = {};
    for (int kt = 0; kt < 16; ++kt) {
        const int cur = kt & 1;
        if (kt < 15) {
            const int ko = (kt + 1) * 32;
            const int bo_ = (cur ^ 1) * 8192;
            gload16(Ag + ko, dA + bo_);
            gload16(Bg + ko, dB + bo_);
        }
        bf8 af[4], bf_[2];
        #pragma unroll
        for (int i = 0; i < 4; ++i) af[i] = *(const bf8*)&Al[cur][aoff[i]];
        #pragma unroll
        for (int i = 0; i < 2; ++i) bf_[i] = *(const bf8*)&Bl[cur][boff[i]];
        #pragma unroll
        for (int mi = 0; mi < 4; ++mi)
            #pragma unroll
            for (int ni = 0; ni < 2; ++ni)
                acc[mi][ni] = MFMA16(af[mi], bf_[ni], acc[mi][ni]);
        __syncthreads();
    }

    #pragma unroll
    for (int mi = 0; mi < 4; ++mi)
    #pragma unroll
    for (int ni = 0; ni < 2; ++ni) {
        const int col = n0 + wc * 32 + ni * 16 + lr;
        const float bs = bo[col];
        const int row0 = m0 + wr * 64 + mi * 16 + lg * 4;
        #pragma unroll
        for (int r = 0; r < 4; ++r)
            out[(size_t)(row0 + r) * HID_ + col] = acc[mi][ni][r] + bs;
    }
}

// ---------------- flash attention: 8 waves x 16 q, K/V staged via global_load_lds ----------------
// 512 blocks (XCD-swizzled) x 512 threads. Swapped-operand MFMA, register softmax,
// defer-max, double-buffered K/V (async direct-to-LDS), pre-clipped bias window.
__global__ __launch_bounds__(512, 4) void k_flash(
    const unsigned short* __restrict__ Q, const unsigned short* __restrict__ K,
    const unsigned short* __restrict__ Vt,
    const float* __restrict__ rel_table, const float* __restrict__ maskadd,
    unsigned short* __restrict__ ctx)
{
    __shared__ unsigned short Klds[2][4096];   // [64 kv][64 d], LDS[r][c]=g[r][c^(r&7)]
    __shared__ unsigned short Vlds[2][4096];   // [64 d][64 kv], same relation
    __shared__ unsigned short Ps[8][16][72];   // wave-private P tile (144B rows, 16B-aligned)
    __shared__ float Tbp[2176];                // pre-clipped bias window * log2e

    const int t = threadIdx.x;
    const int lane = t & 63, w = t >> 6;       // 8 waves
    const int lr = lane & 15, lg = lane >> 4;

    // bijective XCD swizzle: each XCD owns 4 complete (b,h) pairs
    const int flat = blockIdx.x;               // 0..511
    const int idx = flat >> 3;
    const int bh = (flat & 7) * 4 + (idx >> 4);
    const int qb = idx & 15;
    const int b = bh >> 3, h = bh & 7;
    const int q0 = qb * 128;

    // Tbp[j] = log2e * bias(clip(j - q0 - 127)); in-loop j = key - myq + q0 + 127
    for (int i = t; i < 2176; i += 512) {
        int r = i - q0 - 127;
        r = r < -MAXREL ? -MAXREL : (r > MAXREL ? MAXREL : r);
        Tbp[i] = rel_table[(r + MAXREL) * NH_ + h] * LOG2E;
    }

    const unsigned short* Kb = K + (size_t)bh * S_ * HD_;
    const unsigned short* Vb = Vt + (size_t)bh * HD_ * S_;
    const float* mb = maskadd + b * S_;

    const int myq = q0 + w * 16 + lr;
    bf8 qf0, qf1;
    {
        const unsigned short* qg = &Q[((size_t)bh * S_ + myq) * HD_ + lg * 8];
        qf0 = *(const bf8*)qg;
        qf1 = *(const bf8*)(qg + 32);
    }

    // staging: lane l -> tile row w*8 + (l>>3), slot l&7; source col pre-swizzled
    const int srow = w * 8 + (lane >> 3);
    const int scol = ((lane & 7) ^ (srow & 7)) * 8;       // ushorts
    const size_t kbase = (size_t)srow * HD_ + scol;       // + kv*HD_ per tile
    const size_t vbase = (size_t)srow * S_ + scol;        // + kv per tile
    const int woff = w * 1024;                            // byte offset of wave's LDS region

    f4 cacc[4] = {};
    float m_s = -INFINITY, l_s = 0.f;

    // prologue: stage tile 0 into buffer 0
    gload16(&Kb[kbase], (char*)&Klds[0][0] + woff);
    gload16(&Vb[vbase], (char*)&Vlds[0][0] + woff);
    __syncthreads();

    const int xr = lr & 7;
    const int jb0 = 127 - w * 16 - lr + lg * 4;           // + kv0 + nt*16 + r
    for (int ti = 0; ti < 32; ++ti) {
        const int cur = ti & 1;
        const int kv0 = ti * 64;

        // async-stage next tile into buf^1 (can't be sunk; drained by end barrier)
        if (ti < 31) {
            const int nxt = cur ^ 1;
            gload16(&Kb[kbase + (size_t)(kv0 + 64) * HD_], (char*)&Klds[nxt][0] + woff);
            gload16(&Vb[vbase + kv0 + 64], (char*)&Vlds[nxt][0] + woff);
        }

        // mask values (broadcast float4 from L1/L2)
        float4 mk[4];
        #pragma unroll
        for (int nt = 0; nt < 4; ++nt)
            mk[nt] = *(const float4*)&mb[kv0 + nt * 16 + lg * 4];

        // ---- QK^T (swapped): S^T[key][q] ----
        f4 sa[4];
        #pragma unroll
        for (int nt = 0; nt < 4; ++nt) {
            const int row = (nt * 16 + lr) * 64;
            bf8 kf0 = *(const bf8*)&Klds[cur][row + ((0 + lg) ^ xr) * 8];
            bf8 kf1 = *(const bf8*)&Klds[cur][row + ((4 + lg) ^ xr) * 8];
            f4 u = {};
            u = MFMA16(kf0, qf0, u);
            u = MFMA16(kf1, qf1, u);
            sa[nt] = u;
        }

        // ---- bias + mask + tile max (no clamp: Tbp pre-clipped) ----
        float tmax = -INFINITY;
        #pragma unroll
        for (int nt = 0; nt < 4; ++nt) {
            const int jb = jb0 + kv0 + nt * 16;
            #pragma unroll
            for (int r = 0; r < 4; ++r) {
                float mkv = (r == 0) ? mk[nt].x : (r == 1) ? mk[nt].y : (r == 2) ? mk[nt].z : mk[nt].w;
                float sv = sa[nt][r] + Tbp[jb + r] + mkv;
                sa[nt][r] = sv;
                tmax = fmaxf(tmax, sv);
            }
        }
        tmax = fmaxf(tmax, __shfl_xor(tmax, 16));
        tmax = fmaxf(tmax, __shfl_xor(tmax, 32));

        // ---- defer-max (T13, THR=8 in base-2 domain) ----
        if (!__all(tmax <= m_s + 8.0f)) {
            const float mnew = fmaxf(m_s, tmax);
            const float fac = ex2(m_s - mnew);
            l_s *= fac;
            #pragma unroll
            for (int dt = 0; dt < 4; ++dt)
                #pragma unroll
                for (int r = 0; r < 4; ++r) cacc[dt][r] *= fac;
            m_s = mnew;
        }

        float psum = 0.f;
        unsigned int pk[8];
        #pragma unroll
        for (int nt = 0; nt < 4; ++nt) {
            float p0 = ex2(sa[nt][0] - m_s);
            float p1 = ex2(sa[nt][1] - m_s);
            float p2 = ex2(sa[nt][2] - m_s);
            float p3 = ex2(sa[nt][3] - m_s);
            psum += (p0 + p1) + (p2 + p3);
            asm("v_cvt_pk_bf16_f32 %0, %1, %2" : "=v"(pk[nt * 2])     : "v"(p0), "v"(p1));
            asm("v_cvt_pk_bf16_f32 %0, %1, %2" : "=v"(pk[nt * 2 + 1]) : "v"(p2), "v"(p3));
        }
        psum += __shfl_xor(psum, 16);
        psum += __shfl_xor(psum, 32);
        l_s += psum;

        // ---- wave-local P transpose through LDS ----
        #pragma unroll
        for (int nt = 0; nt < 4; ++nt) {
            uint2 pv; pv.x = pk[nt * 2]; pv.y = pk[nt * 2 + 1];
            *(uint2*)&Ps[w][lr][nt * 16 + lg * 4] = pv;
        }
        asm volatile("s_waitcnt lgkmcnt(0)" ::: "memory");
        __builtin_amdgcn_sched_barrier(0);

        // ---- PV (swapped): ctx^T += mfma(V^T, P) ----
        #pragma unroll
        for (int kc = 0; kc < 2; ++kc) {
            bf8 pb = *(const bf8*)&Ps[w][lr][kc * 32 + lg * 8];
            #pragma unroll
            for (int dt = 0; dt < 4; ++dt) {
                const int row = (dt * 16 + lr) * 64;
                bf8 vf = *(const bf8*)&Vlds[cur][row + ((kc * 4 + lg) ^ xr) * 8];
                cacc[dt] = MFMA16(vf, pb, cacc[dt]);
            }
        }
        __syncthreads();   // drains this wave's gload_lds (vmcnt) + gates buffer swap
    }

    // ---- epilogue ----
    const float inv = 1.0f / l_s;
    unsigned short* cg = &ctx[(size_t)(b * S_ + myq) * HID_ + h * HD_];
    #pragma unroll
    for (int dt = 0; dt < 4; ++dt) {
        ushort4 o;
        o.x = f2bf(cacc[dt][0] * inv);
        o.y = f2bf(cacc[dt][1] * inv);
        o.z = f2bf(cacc[dt][2] * inv);
        o.w = f2bf(cacc[dt][3] * inv);
        *(ushort4*)&cg[dt * 16 + lg * 4] = o;
    }
}

// ---------------- launcher ----------------
extern "C" void kernel_launch(void* const* d_in, const int* in_sizes, int n_in,
                              void* d_out, int out_size, void* d_ws, size_t ws_size,
                              hipStream_t stream) {
    const float* hs  = (const float*)d_in[0];
    const float* msk = (const float*)d_in[1];
    const float* Wq  = (const float*)d_in[2];
    const float* bq  = (const float*)d_in[3];
    const float* Wk  = (const float*)d_in[4];
    const float* bk  = (const float*)d_in[5];
    const float* Wv  = (const float*)d_in[6];
    const float* bv  = (const float*)d_in[7];
    const float* Wo  = (const float*)d_in[8];
    const float* bo  = (const float*)d_in[9];
    const float* rel = (const float*)d_in[10];
    float* out = (float*)d_out;

    char* ws = (char*)d_ws;
    unsigned short* hsb = (unsigned short*)ws; ws += (size_t)M_ * HID_ * 2;
    unsigned short* Wqt = (unsigned short*)ws; ws += (size_t)HID_ * HID_ * 2;
    unsigned short* Wkt = (unsigned short*)ws; ws += (size_t)HID_ * HID_ * 2;
    unsigned short* Wvt = (unsigned short*)ws; ws += (size_t)HID_ * HID_ * 2;
    unsigned short* Wot = (unsigned short*)ws; ws += (size_t)HID_ * HID_ * 2;
    unsigned short* Qb  = (unsigned short*)ws; ws += (size_t)M_ * HID_ * 2;
    unsigned short* Kb  = (unsigned short*)ws; ws += (size_t)M_ * HID_ * 2;
    unsigned short* Vtb = (unsigned short*)ws; ws += (size_t)M_ * HID_ * 2;
    unsigned short* ctxb= (unsigned short*)ws; ws += (size_t)M_ * HID_ * 2;
    float* maskadd      = (float*)ws;          ws += (size_t)M_ * 4;

    k_cast_hs<<<(M_ * HID_ / 4 + 255) / 256, 256, 0, stream>>>(hs, hsb, M_ * HID_ / 4);
    k_prep_mask<<<(M_ + 255) / 256, 256, 0, stream>>>(msk, maskadd);
    k_transpose_w4<<<dim3(16, 16, 4), 256, 0, stream>>>(Wq, Wk, Wv, Wo, Wqt, Wkt, Wvt, Wot);
    k_gemm_qkv<<<dim3(64, 12), 256, 0, stream>>>(
        hsb, Wqt, Wkt, Wvt, bq, bk, bv, Qb, Kb, Vtb);
    k_flash<<<512, 512, 0, stream>>>(Qb, Kb, Vtb, rel, maskadd, ctxb);
    k_gemm_out<<<dim3(64, 4), 512, 0, stream>>>(ctxb, Wot, bo, out);
}

// Round 7
// 115.673 us; speedup vs baseline: 3.3843x; 1.0119x over previous
//
#include <hip/hip_runtime.h>
#include <hip/hip_bf16.h>

#define B_    4
#define S_    2048
#define HID_  512
#define NH_   8
#define HD_   64
#define MAXREL 512
#define M_    (B_ * S_)   // 8192 tokens

#define LOG2E 1.44269504f
#define SCALE_Q (0.125f * LOG2E)   // folded into Q at projection time

typedef __attribute__((ext_vector_type(8))) short bf8;            // 8 bf16 (MFMA A/B frag)
typedef __attribute__((ext_vector_type(4))) float f4;             // MFMA C/D frag

static __device__ __forceinline__ unsigned short f2bf(float f) {
    union { float f; unsigned int u; } v; v.f = f;
    unsigned int u = v.u;
    unsigned int r = (u + 0x7FFFu + ((u >> 16) & 1u)) >> 16;   // round-nearest-even
    return (unsigned short)r;
}

static __device__ __forceinline__ float ex2(float x) {   // raw v_exp_f32 (base-2)
    float r; asm("v_exp_f32 %0, %1" : "=v"(r) : "v"(x)); return r;
}

// async global->LDS, 16B per lane; dest = wave-uniform base + lane*16 (linear)
static __device__ __forceinline__ void gload16(const void* g, void* l) {
    __builtin_amdgcn_global_load_lds(
        (const __attribute__((address_space(1))) unsigned int*)g,
        (__attribute__((address_space(3))) unsigned int*)l, 16, 0, 0);
}

#define MFMA16(a, b, c) __builtin_amdgcn_mfma_f32_16x16x32_bf16((a), (b), (c), 0, 0, 0)

// ---------------- cast hidden_states fp32 -> bf16 ----------------
__global__ void k_cast_hs(const float* __restrict__ src, unsigned short* __restrict__ dst, int n4) {
    int i = blockIdx.x * blockDim.x + threadIdx.x;
    if (i >= n4) return;
    float4 v = ((const float4*)src)[i];
    ushort4 o;
    o.x = f2bf(v.x); o.y = f2bf(v.y); o.z = f2bf(v.z); o.w = f2bf(v.w);
    ((ushort4*)dst)[i] = o;
}

// ---------------- mask -> additive form (0 attend / -3e38 masked) ----------------
__global__ void k_prep_mask(const float* __restrict__ mask, float* __restrict__ maskadd) {
    int i = blockIdx.x * blockDim.x + threadIdx.x;
    if (i < M_) maskadd[i] = (1.0f - mask[i]) * -3.0e38f;
}

// ---------------- transpose + cast 4 weights (LDS 32x32 tiles) ----------------
__global__ void k_transpose_w4(const float* __restrict__ W0, const float* __restrict__ W1,
                               const float* __restrict__ W2, const float* __restrict__ W3,
                               unsigned short* __restrict__ T0, unsigned short* __restrict__ T1,
                               unsigned short* __restrict__ T2, unsigned short* __restrict__ T3) {
    __shared__ float tile[32][33];
    const int z = blockIdx.z;
    const float* W = (z == 0) ? W0 : (z == 1) ? W1 : (z == 2) ? W2 : W3;
    unsigned short* T = (z == 0) ? T0 : (z == 1) ? T1 : (z == 2) ? T2 : T3;
    const int tx = threadIdx.x & 31, ty = threadIdx.x >> 5;   // 256 thr
    const int n0 = blockIdx.x * 32, k0 = blockIdx.y * 32;
    #pragma unroll
    for (int i = 0; i < 4; ++i)
        tile[ty + i * 8][tx] = W[(size_t)(k0 + ty + i * 8) * HID_ + n0 + tx];
    __syncthreads();
    #pragma unroll
    for (int i = 0; i < 4; ++i)
        T[(size_t)(n0 + ty + i * 8) * HID_ + k0 + tx] = f2bf(tile[tx][ty + i * 8]);
}

// ---------------- fused QKV GEMM: 128x128 tile, dbuf LDS via global_load_lds ----------------
// A[8192,512] bf16 x Wt(z)[512,512] -> z=0: Q (pre-scaled), z=1: K, z=2: Vt[b,h,d,s]
__global__ __launch_bounds__(256, 3) void k_gemm_qkv(
    const unsigned short* __restrict__ Abf,
    const unsigned short* __restrict__ Wqt, const unsigned short* __restrict__ Wkt,
    const unsigned short* __restrict__ Wvt,
    const float* __restrict__ bq, const float* __restrict__ bk, const float* __restrict__ bv,
    unsigned short* __restrict__ Q, unsigned short* __restrict__ K, unsigned short* __restrict__ Vt)
{
    __shared__ unsigned short Al[2][128 * 32];
    __shared__ unsigned short Bl[2][128 * 32];

    const int t = threadIdx.x;
    const int lane = t & 63, w = t >> 6;
    const int lr = lane & 15, lg = lane >> 4;
    const int wr = w >> 1, wc = w & 1;

    const int m0 = blockIdx.x * 128;
    const int ng = blockIdx.y * 128;
    const int z = ng >> 9;
    const int n0 = ng & 511;
    const unsigned short* Wt = (z == 0) ? Wqt : ((z == 1) ? Wkt : Wvt);
    const float* bias = (z == 0) ? bq : ((z == 1) ? bk : bv);
    const float osc = (z == 0) ? SCALE_Q : 1.0f;

    // staging: thread t -> row t>>2, slot t&3; source col pre-swizzled, LDS dest linear
    const int srow = t >> 2;
    const int sc = (((t & 3) ^ ((srow >> 1) & 3))) * 8;     // swizzled source col (ushorts)
    const unsigned short* Ag0 = &Abf[(size_t)(m0 + srow) * HID_ + sc];
    const unsigned short* Ag1 = &Abf[(size_t)(m0 + 64 + srow) * HID_ + sc];
    const unsigned short* Bg0 = &Wt[(size_t)(n0 + srow) * HID_ + sc];
    const unsigned short* Bg1 = &Wt[(size_t)(n0 + 64 + srow) * HID_ + sc];
    // wave-uniform LDS dest bases (this wave covers rows w*16..w*16+15 of each half)
    char* dA0 = (char*)&Al[0][0] + w * 1024;   // + buf*8192 applied in loop
    char* dB0 = (char*)&Bl[0][0] + w * 1024;

    // fragment read offsets (read-side swizzle matches source pre-swizzle)
    const int fx = (lr >> 1) & 3;
    int aoff[4], boff[4];
    #pragma unroll
    for (int i = 0; i < 4; ++i) {
        aoff[i] = (wr * 64 + i * 16 + lr) * 32 + ((lg ^ fx) * 8);
        boff[i] = (wc * 64 + i * 16 + lr) * 32 + ((lg ^ fx) * 8);
    }

    // prologue: stage k0=0 into buf 0
    gload16(Ag0, dA0);
    gload16(Ag1, dA0 + 4096);
    gload16(Bg0, dB0);
    gload16(Bg1, dB0 + 4096);
    __syncthreads();

    f4 acc[4][4] = {};
    for (int kt = 0; kt < 16; ++kt) {
        const int cur = kt & 1;
        if (kt < 15) {
            const int ko = (kt + 1) * 32;
            const int bo = (cur ^ 1) * 8192;
            gload16(Ag0 + ko, dA0 + bo);
            gload16(Ag1 + ko, dA0 + bo + 4096);
            gload16(Bg0 + ko, dB0 + bo);
            gload16(Bg1 + ko, dB0 + bo + 4096);
        }
        bf8 af[4], bf_[4];
        #pragma unroll
        for (int i = 0; i < 4; ++i) {
            af[i]  = *(const bf8*)&Al[cur][aoff[i]];
            bf_[i] = *(const bf8*)&Bl[cur][boff[i]];
        }
        #pragma unroll
        for (int mi = 0; mi < 4; ++mi)
            #pragma unroll
            for (int ni = 0; ni < 4; ++ni)
                acc[mi][ni] = MFMA16(af[mi], bf_[ni], acc[mi][ni]);
        __syncthreads();
    }

    // epilogue: scatter per layout
    #pragma unroll
    for (int mi = 0; mi < 4; ++mi)
    #pragma unroll
    for (int ni = 0; ni < 4; ++ni) {
        const int col = n0 + wc * 64 + ni * 16 + lr;    // hid within section
        const int h = col >> 6, d = col & 63;
        const float bs = bias[col];
        const int row0 = m0 + wr * 64 + mi * 16 + lg * 4;
        const int b = row0 >> 11, s0 = row0 & 2047;
        if (z == 2) {
            ushort4 o;
            o.x = f2bf(acc[mi][ni][0] + bs);
            o.y = f2bf(acc[mi][ni][1] + bs);
            o.z = f2bf(acc[mi][ni][2] + bs);
            o.w = f2bf(acc[mi][ni][3] + bs);
            *(ushort4*)&Vt[(((size_t)(b * NH_ + h)) * HD_ + d) * S_ + s0] = o;
        } else {
            unsigned short* dst = (z == 0) ? Q : K;
            #pragma unroll
            for (int r = 0; r < 4; ++r) {
                float v = (acc[mi][ni][r] + bs) * osc;
                dst[(((size_t)(b * NH_ + h)) * S_ + s0 + r) * HD_ + d] = f2bf(v);
            }
        }
    }
}

// ---------------- output projection GEMM: 128x128 tile, 512 threads ----------------
__global__ __launch_bounds__(512) void k_gemm_out(
    const unsigned short* __restrict__ Abf,
    const unsigned short* __restrict__ Wot,
    const float* __restrict__ bo,
    float* __restrict__ out)
{
    __shared__ unsigned short Al[2][128 * 32];
    __shared__ unsigned short Bl[2][128 * 32];

    const int t = threadIdx.x;
    const int lane = t & 63, w = t >> 6;          // 8 waves, 2x4
    const int lr = lane & 15, lg = lane >> 4;
    const int wr = w >> 2, wc = w & 3;

    const int m0 = blockIdx.x * 128;
    const int n0 = blockIdx.y * 128;

    const int srow = t >> 2;
    const int sc = (((t & 3) ^ ((srow >> 1) & 3))) * 8;
    const unsigned short* Ag = &Abf[(size_t)(m0 + srow) * HID_ + sc];
    const unsigned short* Bg = &Wot[(size_t)(n0 + srow) * HID_ + sc];
    char* dA = (char*)&Al[0][0] + w * 1024;
    char* dB = (char*)&Bl[0][0] + w * 1024;

    const int fx = (lr >> 1) & 3;
    int aoff[4], boff[2];
    #pragma unroll
    for (int i = 0; i < 4; ++i)
        aoff[i] = (wr * 64 + i * 16 + lr) * 32 + ((lg ^ fx) * 8);
    #pragma unroll
    for (int i = 0; i < 2; ++i)
        boff[i] = (wc * 32 + i * 16 + lr) * 32 + ((lg ^ fx) * 8);

    gload16(Ag, dA);
    gload16(Bg, dB);
    __syncthreads();

    f4 acc[4][2] = {};
    for (int kt = 0; kt < 16; ++kt) {
        const int cur = kt & 1;
        if (kt < 15) {
            const int ko = (kt + 1) * 32;
            const int bo_ = (cur ^ 1) * 8192;
            gload16(Ag + ko, dA + bo_);
            gload16(Bg + ko, dB + bo_);
        }
        bf8 af[4], bf_[2];
        #pragma unroll
        for (int i = 0; i < 4; ++i) af[i] = *(const bf8*)&Al[cur][aoff[i]];
        #pragma unroll
        for (int i = 0; i < 2; ++i) bf_[i] = *(const bf8*)&Bl[cur][boff[i]];
        #pragma unroll
        for (int mi = 0; mi < 4; ++mi)
            #pragma unroll
            for (int ni = 0; ni < 2; ++ni)
                acc[mi][ni] = MFMA16(af[mi], bf_[ni], acc[mi][ni]);
        __syncthreads();
    }

    #pragma unroll
    for (int mi = 0; mi < 4; ++mi)
    #pragma unroll
    for (int ni = 0; ni < 2; ++ni) {
        const int col = n0 + wc * 32 + ni * 16 + lr;
        const float bs = bo[col];
        const int row0 = m0 + wr * 64 + mi * 16 + lg * 4;
        #pragma unroll
        for (int r = 0; r < 4; ++r)
            out[(size_t)(row0 + r) * HID_ + col] = acc[mi][ni][r] + bs;
    }
}

// ---------------- flash attention: 8 waves x 16 q, K/V via global_load_lds,
//   uniform-tile bias fast path, lane-partial l, speculative exp (defer-max) ----------------
__global__ __launch_bounds__(512, 4) void k_flash(
    const unsigned short* __restrict__ Q, const unsigned short* __restrict__ K,
    const unsigned short* __restrict__ Vt,
    const float* __restrict__ rel_table, const float* __restrict__ maskadd,
    unsigned short* __restrict__ ctx)
{
    __shared__ unsigned short Klds[2][4096];   // [64 kv][64 d], LDS[r][c]=g[r][c^(r&7)]
    __shared__ unsigned short Vlds[2][4096];   // [64 d][64 kv], same relation
    __shared__ unsigned short Ps[8][16][72];   // wave-private P tile
    __shared__ float Tbp[2176];                // pre-clipped bias window * log2e

    const int t = threadIdx.x;
    const int lane = t & 63, w = t >> 6;       // 8 waves
    const int lr = lane & 15, lg = lane >> 4;

    // bijective XCD swizzle: each XCD owns 4 complete (b,h) pairs
    const int flat = blockIdx.x;               // 0..511
    const int idx = flat >> 3;
    const int bh = (flat & 7) * 4 + (idx >> 4);
    const int qb = idx & 15;
    const int b = bh >> 3, h = bh & 7;
    const int q0 = qb * 128;

    // Tbp[j] = log2e * bias(clip(j - q0 - 127)); in-loop j = key - myq + q0 + 127
    for (int i = t; i < 2176; i += 512) {
        int r = i - q0 - 127;
        r = r < -MAXREL ? -MAXREL : (r > MAXREL ? MAXREL : r);
        Tbp[i] = rel_table[(r + MAXREL) * NH_ + h] * LOG2E;
    }
    // table-edge constants for fully-clipped tiles
    const float TbLo = rel_table[h] * LOG2E;                    // rel = -512
    const float TbHi = rel_table[2 * MAXREL * NH_ + h] * LOG2E; // rel = +512

    const unsigned short* Kb = K + (size_t)bh * S_ * HD_;
    const unsigned short* Vb = Vt + (size_t)bh * HD_ * S_;
    const float* mb = maskadd + b * S_;

    const int myq = q0 + w * 16 + lr;
    const int qw = q0 + w * 16;                // wave q base (wave-uniform)
    bf8 qf0, qf1;
    {
        const unsigned short* qg = &Q[((size_t)bh * S_ + myq) * HD_ + lg * 8];
        qf0 = *(const bf8*)qg;
        qf1 = *(const bf8*)(qg + 32);
    }

    // staging: lane l -> tile row w*8 + (l>>3), slot l&7; source col pre-swizzled
    const int srow = w * 8 + (lane >> 3);
    const int scol = ((lane & 7) ^ (srow & 7)) * 8;       // ushorts
    const size_t kbase = (size_t)srow * HD_ + scol;       // + kv*HD_ per tile
    const size_t vbase = (size_t)srow * S_ + scol;        // + kv per tile
    const int woff = w * 1024;                            // byte offset of wave's LDS region

    f4 cacc[4] = {};
    float m_s = -INFINITY, lsum = 0.f;                    // lane-partial l

    // prologue: stage tile 0 into buffer 0
    gload16(&Kb[kbase], (char*)&Klds[0][0] + woff);
    gload16(&Vb[vbase], (char*)&Vlds[0][0] + woff);
    __syncthreads();

    const int xr = lr & 7;
    const int jb0 = 127 - w * 16 - lr + lg * 4;           // + kv0 + nt*16 + r
    for (int ti = 0; ti < 32; ++ti) {
        const int cur = ti & 1;
        const int kv0 = ti * 64;

        // async-stage next tile into buf^1 (drained by end barrier)
        if (ti < 31) {
            const int nxt = cur ^ 1;
            gload16(&Kb[kbase + (size_t)(kv0 + 64) * HD_], (char*)&Klds[nxt][0] + woff);
            gload16(&Vb[vbase + kv0 + 64], (char*)&Vlds[nxt][0] + woff);
        }

        // mask values (broadcast float4 from L1/L2)
        float4 mk[4];
        #pragma unroll
        for (int nt = 0; nt < 4; ++nt)
            mk[nt] = *(const float4*)&mb[kv0 + nt * 16 + lg * 4];

        // ---- QK^T (swapped): S^T[key][q] ----
        f4 sa[4];
        #pragma unroll
        for (int nt = 0; nt < 4; ++nt) {
            const int row = (nt * 16 + lr) * 64;
            bf8 kf0 = *(const bf8*)&Klds[cur][row + ((0 + lg) ^ xr) * 8];
            bf8 kf1 = *(const bf8*)&Klds[cur][row + ((4 + lg) ^ xr) * 8];
            f4 u = {};
            u = MFMA16(kf0, qf0, u);
            u = MFMA16(kf1, qf1, u);
            sa[nt] = u;
        }

        // ---- bias + mask + local max; uniform-tile fast path skips the gather ----
        float tmaxl = -INFINITY;
        const bool uniLo = (kv0 + 63 - qw <= -MAXREL);    // all rel <= -512
        const bool uniHi = (kv0 - qw - 15 >= MAXREL);     // all rel >= +512
        if (uniLo || uniHi) {
            const float biasC = uniLo ? TbLo : TbHi;
            #pragma unroll
            for (int nt = 0; nt < 4; ++nt) {
                #pragma unroll
                for (int r = 0; r < 4; ++r) {
                    float mkv = (r == 0) ? mk[nt].x : (r == 1) ? mk[nt].y : (r == 2) ? mk[nt].z : mk[nt].w;
                    float sv = sa[nt][r] + (biasC + mkv);
                    sa[nt][r] = sv;
                    tmaxl = fmaxf(tmaxl, sv);
                }
            }
        } else {
            const int jb = jb0 + kv0;
            #pragma unroll
            for (int nt = 0; nt < 4; ++nt) {
                #pragma unroll
                for (int r = 0; r < 4; ++r) {
                    float mkv = (r == 0) ? mk[nt].x : (r == 1) ? mk[nt].y : (r == 2) ? mk[nt].z : mk[nt].w;
                    float sv = sa[nt][r] + (Tbp[jb + nt * 16 + r] + mkv);
                    sa[nt][r] = sv;
                    tmaxl = fmaxf(tmaxl, sv);
                }
            }
        }
        // tmax reduce in flight while speculative exps issue below
        float tmax = fmaxf(tmaxl, __shfl_xor(tmaxl, 16));
        tmax = fmaxf(tmax, __shfl_xor(tmax, 32));

        // ---- speculative exp with current m_s (valid when deferred — common case) ----
        float ptile = 0.f;
        unsigned int pk[8];
        #pragma unroll
        for (int nt = 0; nt < 4; ++nt) {
            float p0 = ex2(sa[nt][0] - m_s);
            float p1 = ex2(sa[nt][1] - m_s);
            float p2 = ex2(sa[nt][2] - m_s);
            float p3 = ex2(sa[nt][3] - m_s);
            ptile += (p0 + p1) + (p2 + p3);
            asm("v_cvt_pk_bf16_f32 %0, %1, %2" : "=v"(pk[nt * 2])     : "v"(p0), "v"(p1));
            asm("v_cvt_pk_bf16_f32 %0, %1, %2" : "=v"(pk[nt * 2 + 1]) : "v"(p2), "v"(p3));
        }
        if (!__all(tmax <= m_s + 8.0f)) {     // rare: rescale + recompute
            const float mnew = fmaxf(m_s, tmax);
            const float fac = ex2(m_s - mnew);
            lsum *= fac;
            #pragma unroll
            for (int dt = 0; dt < 4; ++dt)
                #pragma unroll
                for (int r = 0; r < 4; ++r) cacc[dt][r] *= fac;
            ptile = 0.f;
            #pragma unroll
            for (int nt = 0; nt < 4; ++nt) {
                float p0 = ex2(sa[nt][0] - mnew);
                float p1 = ex2(sa[nt][1] - mnew);
                float p2 = ex2(sa[nt][2] - mnew);
                float p3 = ex2(sa[nt][3] - mnew);
                ptile += (p0 + p1) + (p2 + p3);
                asm("v_cvt_pk_bf16_f32 %0, %1, %2" : "=v"(pk[nt * 2])     : "v"(p0), "v"(p1));
                asm("v_cvt_pk_bf16_f32 %0, %1, %2" : "=v"(pk[nt * 2 + 1]) : "v"(p2), "v"(p3));
            }
            m_s = mnew;
        }
        lsum += ptile;

        // ---- wave-local P transpose through LDS ----
        #pragma unroll
        for (int nt = 0; nt < 4; ++nt) {
            uint2 pv; pv.x = pk[nt * 2]; pv.y = pk[nt * 2 + 1];
            *(uint2*)&Ps[w][lr][nt * 16 + lg * 4] = pv;
        }
        asm volatile("s_waitcnt lgkmcnt(0)" ::: "memory");
        __builtin_amdgcn_sched_barrier(0);

        // ---- PV (swapped): ctx^T += mfma(V^T, P) ----
        #pragma unroll
        for (int kc = 0; kc < 2; ++kc) {
            bf8 pb = *(const bf8*)&Ps[w][lr][kc * 32 + lg * 8];
            #pragma unroll
            for (int dt = 0; dt < 4; ++dt) {
                const int row = (dt * 16 + lr) * 64;
                bf8 vf = *(const bf8*)&Vlds[cur][row + ((kc * 4 + lg) ^ xr) * 8];
                cacc[dt] = MFMA16(vf, pb, cacc[dt]);
            }
        }
        __syncthreads();   // drains gload_lds (vmcnt) + gates buffer swap
    }

    // ---- epilogue: single l reduce, divide, write ----
    lsum += __shfl_xor(lsum, 16);
    lsum += __shfl_xor(lsum, 32);
    const float inv = 1.0f / lsum;
    unsigned short* cg = &ctx[(size_t)(b * S_ + myq) * HID_ + h * HD_];
    #pragma unroll
    for (int dt = 0; dt < 4; ++dt) {
        ushort4 o;
        o.x = f2bf(cacc[dt][0] * inv);
        o.y = f2bf(cacc[dt][1] * inv);
        o.z = f2bf(cacc[dt][2] * inv);
        o.w = f2bf(cacc[dt][3] * inv);
        *(ushort4*)&cg[dt * 16 + lg * 4] = o;
    }
}

// ---------------- launcher ----------------
extern "C" void kernel_launch(void* const* d_in, const int* in_sizes, int n_in,
                              void* d_out, int out_size, void* d_ws, size_t ws_size,
                              hipStream_t stream) {
    const float* hs  = (const float*)d_in[0];
    const float* msk = (const float*)d_in[1];
    const float* Wq  = (const float*)d_in[2];
    const float* bq  = (const float*)d_in[3];
    const float* Wk  = (const float*)d_in[4];
    const float* bk  = (const float*)d_in[5];
    const float* Wv  = (const float*)d_in[6];
    const float* bv  = (const float*)d_in[7];
    const float* Wo  = (const float*)d_in[8];
    const float* bo  = (const float*)d_in[9];
    const float* rel = (const float*)d_in[10];
    float* out = (float*)d_out;

    char* ws = (char*)d_ws;
    unsigned short* hsb = (unsigned short*)ws; ws += (size_t)M_ * HID_ * 2;
    unsigned short* Wqt = (unsigned short*)ws; ws += (size_t)HID_ * HID_ * 2;
    unsigned short* Wkt = (unsigned short*)ws; ws += (size_t)HID_ * HID_ * 2;
    unsigned short* Wvt = (unsigned short*)ws; ws += (size_t)HID_ * HID_ * 2;
    unsigned short* Wot = (unsigned short*)ws; ws += (size_t)HID_ * HID_ * 2;
    unsigned short* Qb  = (unsigned short*)ws; ws += (size_t)M_ * HID_ * 2;
    unsigned short* Kb  = (unsigned short*)ws; ws += (size_t)M_ * HID_ * 2;
    unsigned short* Vtb = (unsigned short*)ws; ws += (size_t)M_ * HID_ * 2;
    unsigned short* ctxb= (unsigned short*)ws; ws += (size_t)M_ * HID_ * 2;
    float* maskadd      = (float*)ws;          ws += (size_t)M_ * 4;

    k_cast_hs<<<(M_ * HID_ / 4 + 255) / 256, 256, 0, stream>>>(hs, hsb, M_ * HID_ / 4);
    k_prep_mask<<<(M_ + 255) / 256, 256, 0, stream>>>(msk, maskadd);
    k_transpose_w4<<<dim3(16, 16, 4), 256, 0, stream>>>(Wq, Wk, Wv, Wo, Wqt, Wkt, Wvt, Wot);
    k_gemm_qkv<<<dim3(64, 12), 256, 0, stream>>>(
        hsb, Wqt, Wkt, Wvt, bq, bk, bv, Qb, Kb, Vtb);
    k_flash<<<512, 512, 0, stream>>>(Qb, Kb, Vtb, rel, maskadd, ctxb);
    k_gemm_out<<<dim3(64, 4), 512, 0, stream>>>(ctxb, Wot, bo, out);
}